// Round 1
// baseline (768.484 us; speedup 1.0000x reference)
//
#include <hip/hip_runtime.h>

#define T 2048
#define D 1024
#define F 4096
#define E 8
#define NS 8
#define FS 512
#define SHB 5120      // shared-expert H base row (routed padded capacity)
#define NROWS 7168    // SHB + T
#define MT_MAX 56     // NROWS/128

typedef float floatx4 __attribute__((ext_vector_type(4)));
typedef short short8 __attribute__((ext_vector_type(8)));

__device__ __forceinline__ unsigned short f2bf(float f) {
  unsigned int u = __float_as_uint(f);
  u += 0x7FFF + ((u >> 16) & 1);   // RNE
  return (unsigned short)(u >> 16);
}

__device__ __forceinline__ void glds16(const void* g, void* l) {
  __builtin_amdgcn_global_load_lds(
      (const __attribute__((address_space(1))) void*)g,
      (__attribute__((address_space(3))) void*)l, 16, 0, 0);
}

// ---------------- gate: logits, softmax, top-2, x -> bf16 ----------------
__global__ void gate_kernel(const float* __restrict__ x, const float* __restrict__ gW,
                            unsigned short* __restrict__ xb, int* __restrict__ cnt,
                            int* __restrict__ list_tok, float* __restrict__ list_gate) {
  int t = blockIdx.x, tid = threadIdx.x;
  const float* xr = x + (size_t)t * D;
  float acc[E];
#pragma unroll
  for (int e = 0; e < E; ++e) acc[e] = 0.f;
  for (int d = tid; d < D; d += 256) {
    float xv = xr[d];
    xb[(size_t)t * D + d] = f2bf(xv);
#pragma unroll
    for (int e = 0; e < E; ++e) acc[e] += xv * gW[e * D + d];
  }
#pragma unroll
  for (int o = 32; o > 0; o >>= 1)
#pragma unroll
    for (int e = 0; e < E; ++e) acc[e] += __shfl_down(acc[e], o, 64);
  __shared__ float wred[4][E];
  int lane = tid & 63, wv = tid >> 6;
  if (lane == 0)
#pragma unroll
    for (int e = 0; e < E; ++e) wred[wv][e] = acc[e];
  __syncthreads();
  if (tid == 0) {
    float l[E];
#pragma unroll
    for (int e = 0; e < E; ++e) l[e] = wred[0][e] + wred[1][e] + wred[2][e] + wred[3][e];
    int i1 = 0; float m1 = l[0];
    for (int e = 1; e < E; ++e) if (l[e] > m1) { m1 = l[e]; i1 = e; }
    int i2 = -1; float m2 = -3.4e38f;
    for (int e = 0; e < E; ++e) if (e != i1 && l[e] > m2) { m2 = l[e]; i2 = e; }
    float s = 0.f, p[E];
#pragma unroll
    for (int e = 0; e < E; ++e) { p[e] = __expf(l[e] - m1); s += p[e]; }
    float inv = 1.f / s;
    int p1 = atomicAdd(&cnt[i1], 1);
    list_tok[i1 * T + p1] = t; list_gate[i1 * T + p1] = p[i1] * inv;
    int p2 = atomicAdd(&cnt[i2], 1);
    list_tok[i2 * T + p2] = t; list_gate[i2 * T + p2] = p[i2] * inv;
  }
}

// ---------------- offsets (1 thread): 128-aligned segment starts ----------------
__global__ void offsets_kernel(const int* __restrict__ cnt, int* __restrict__ off,
                               int* __restrict__ mt_expert) {
  if (threadIdx.x == 0 && blockIdx.x == 0) {
    int o = 0;
    for (int e = 0; e < E; ++e) { off[e] = o; o += (cnt[e] + 127) & ~127; }
    off[E] = o;
    for (int i = 0; i < MT_MAX; ++i) mt_expert[i] = -1;
    for (int e = 0; e < E; ++e) {
      int t0 = off[e] >> 7, nt = (cnt[e] + 127) >> 7;
      for (int i = 0; i < nt; ++i) mt_expert[t0 + i] = e;
    }
    for (int i = SHB >> 7; i < MT_MAX; ++i) mt_expert[i] = E;
  }
}

// ---------------- scatter: row maps + per-row scales ----------------
__global__ void scatter_kernel(const int* __restrict__ cnt, const int* __restrict__ off,
                               const int* __restrict__ list_tok, const float* __restrict__ list_gate,
                               int* __restrict__ tok_of_row, float* __restrict__ row_scale,
                               int* __restrict__ tok_rows, int* __restrict__ tk) {
  int idx = blockIdx.x * 256 + threadIdx.x;  // E*T
  int e = idx >> 11, i = idx & (T - 1);
  if (e < E && i < cnt[e]) {
    int row = off[e] + i;
    int t = list_tok[e * T + i];
    tok_of_row[row] = t;
    row_scale[row] = 0.5f * list_gate[e * T + i];
    int k = atomicAdd(&tk[t], 1);
    tok_rows[2 * t + k] = row;
  }
}

// ------- transpose+cast fp32 [R,C] -> bf16 B^T tiled [C/128][R/32][128][32] -------
// 32r x 32c tile, 256 threads: 1 float4 read pass + 1 ushort4 write pass
__global__ void transpose_cast(const float* __restrict__ in, unsigned short* __restrict__ out,
                               int R, int C) {
  in += (size_t)blockIdx.z * R * C;
  out += (size_t)blockIdx.z * R * C;
  int r0 = blockIdx.y * 32, c0 = blockIdx.x * 32;
  __shared__ float tile[32][33];
  int tid = threadIdx.x;
  {
    int rl = tid >> 3, cl = (tid & 7) * 4;
    float4 v = *(const float4*)(in + (size_t)(r0 + rl) * C + c0 + cl);
    tile[rl][cl] = v.x; tile[rl][cl + 1] = v.y;
    tile[rl][cl + 2] = v.z; tile[rl][cl + 3] = v.w;
  }
  __syncthreads();
  {
    int cl = tid >> 3, rq = (tid & 7) * 4;
    int c = c0 + cl, r = r0 + rq;
    ushort4 v;
    v.x = f2bf(tile[rq][cl]);     v.y = f2bf(tile[rq + 1][cl]);
    v.z = f2bf(tile[rq + 2][cl]); v.w = f2bf(tile[rq + 3][cl]);
    int Rt = R >> 5;
    size_t o = ((size_t)(c >> 7) * Rt + (r >> 5)) * 4096 + (size_t)(c & 127) * 32 + (r & 31);
    *(ushort4*)(out + o) = v;
  }
}

// ---------------- up GEMM: H = silu(A@W1) * (A@W3), grouped by expert ----------------
// 2-phase double-buffered: stage(kt+1) issued before compute(kt); one barrier/K-step.
// LDS XOR-swizzle: 16B slot j of row r holds global slot j ^ ((r>>1)&3).
// A is staged via global_load_lds with PRE-SWIZZLED per-lane global source (m173
// pattern): LDS dest stays linear (wave base + lane*16), the source slot carries
// the same XOR the read side expects.
__global__ __launch_bounds__(256, 2) void up_gemm(
    const unsigned short* __restrict__ xb, const unsigned short* __restrict__ W1T,
    const unsigned short* __restrict__ W3T, const unsigned short* __restrict__ W1sT,
    const unsigned short* __restrict__ W3sT, const int* __restrict__ mt_expert,
    const int* __restrict__ tok_of_row, unsigned short* __restrict__ Hb) {
  int mt = blockIdx.y, ntile = blockIdx.x;
  int e = mt_expert[mt];
  if (e < 0) return;
  const unsigned short *B1, *B3;
  if (e < E) {
    B1 = W1T + (size_t)e * F * D;
    B3 = W3T + (size_t)e * F * D;
  } else {
    B1 = W1sT; B3 = W3sT;
  }
  __shared__ unsigned short Al[2][128 * 32];
  __shared__ unsigned short B1l[2][128 * 32];
  __shared__ unsigned short B3l[2][128 * 32];
  int tid = threadIdx.x;
  int lane = tid & 63, wv = tid >> 6, wm = wv >> 1, wn = wv & 1;
  int row16 = lane & 15, quad = lane >> 4;
  int qsw8 = (quad ^ ((lane >> 1) & 3)) * 8;   // swizzled read slot, in shorts
  int swzb = (tid >> 2) * 64 + (((tid & 3) ^ ((tid >> 3) & 3)) * 16);  // staging src byte off
  int lw = wv * 1024;  // wave LDS byte offset (glds dest must be wave-uniform)

  // A gather: thread stages row r1 = tid>>2 (call 1) and r1+64 (call 2), 16B slot
  // (tid&3) ^ sa(row); sa(row) = (row>>1)&3 = (tid>>3)&3 for BOTH rows (64 even).
  int r1 = tid >> 2;
  int hrow1 = mt * 128 + r1, hrow2 = hrow1 + 64;
  int srow1 = (e < E) ? tok_of_row[hrow1] : (hrow1 - SHB);
  int srow2 = (e < E) ? tok_of_row[hrow2] : (hrow2 - SHB);
  int asl = ((tid & 3) ^ ((tid >> 3) & 3)) * 16;
  const char* asrc1 = (const char*)(xb + (size_t)srow1 * D) + asl;
  const char* asrc2 = (const char*)(xb + (size_t)srow2 * D) + asl;
  const char* b1t = (const char*)(B1 + (size_t)ntile * (D / 32) * 4096);
  const char* b3t = (const char*)(B3 + (size_t)ntile * (D / 32) * 4096);

  floatx4 accg[4][4], accu[4][4];
#pragma unroll
  for (int i = 0; i < 4; ++i)
#pragma unroll
    for (int j = 0; j < 4; ++j) {
      accg[i][j] = (floatx4){0.f, 0.f, 0.f, 0.f};
      accu[i][j] = (floatx4){0.f, 0.f, 0.f, 0.f};
    }

  auto stage = [&](int kt, int b) {
    size_t ko = (size_t)kt * 64;     // A advances 32 bf16 = 64 B per K-step
    size_t bo = (size_t)kt * 8192;   // B tile = 8 KB per K-step
    glds16(asrc1 + ko, (char*)Al[b] + lw);
    glds16(asrc2 + ko, (char*)Al[b] + 4096 + lw);
    glds16(b1t + bo + swzb, (char*)B1l[b] + lw);
    glds16(b1t + bo + 4096 + swzb, (char*)B1l[b] + 4096 + lw);
    glds16(b3t + bo + swzb, (char*)B3l[b] + lw);
    glds16(b3t + bo + 4096 + swzb, (char*)B3l[b] + 4096 + lw);
  };

  stage(0, 0);
  __syncthreads();
  int cur = 0;
  for (int kt = 0; kt < D / 32; ++kt) {
    if (kt + 1 < D / 32) stage(kt + 1, cur ^ 1);  // prefetch: in flight during MFMA
    const unsigned short* Ac = Al[cur];
    const unsigned short* B1c = B1l[cur];
    const unsigned short* B3c = B3l[cur];
    short8 af[4], b1f[4], b3f[4];
#pragma unroll
    for (int mi = 0; mi < 4; ++mi)
      af[mi] = *(const short8*)(Ac + (wm * 64 + mi * 16 + row16) * 32 + qsw8);
#pragma unroll
    for (int ni = 0; ni < 4; ++ni) {
      b1f[ni] = *(const short8*)(B1c + (wn * 64 + ni * 16 + row16) * 32 + qsw8);
      b3f[ni] = *(const short8*)(B3c + (wn * 64 + ni * 16 + row16) * 32 + qsw8);
    }
#pragma unroll
    for (int mi = 0; mi < 4; ++mi)
#pragma unroll
      for (int ni = 0; ni < 4; ++ni) {
        accg[mi][ni] = __builtin_amdgcn_mfma_f32_16x16x32_bf16(af[mi], b1f[ni], accg[mi][ni], 0, 0, 0);
        accu[mi][ni] = __builtin_amdgcn_mfma_f32_16x16x32_bf16(af[mi], b3f[ni], accu[mi][ni], 0, 0, 0);
      }
    __syncthreads();  // drains prefetch (vmcnt0) AFTER a full MFMA phase
    cur ^= 1;
  }
  // epilogue: silu(g)*u -> bf16, H in tiled layout
#pragma unroll
  for (int mi = 0; mi < 4; ++mi)
#pragma unroll
    for (int ni = 0; ni < 4; ++ni)
#pragma unroll
      for (int r = 0; r < 4; ++r) {
        int hrow = mt * 128 + wm * 64 + mi * 16 + quad * 4 + r;
        int col = ntile * 128 + wn * 64 + ni * 16 + row16;
        float g = accg[mi][ni][r], u = accu[mi][ni][r];
        float h = g * u / (1.0f + __expf(-g));
        size_t o = ((size_t)(hrow >> 7) * 128 + (col >> 5)) * 4096 + (size_t)(hrow & 127) * 32 + (col & 31);
        Hb[o] = f2bf(h);
      }
}

// ---------------- down GEMM: O = (H @ W2) * row_scale, split-K x2 ----------------
// Same 2-phase double-buffered schedule.
__global__ __launch_bounds__(256, 2) void down_gemm(
    const unsigned short* __restrict__ Hb, const unsigned short* __restrict__ W2T,
    const unsigned short* __restrict__ W2sT, const int* __restrict__ mt_expert,
    const float* __restrict__ row_scale, float* __restrict__ O) {
  int mt = blockIdx.y, ntile = blockIdx.x, kz = blockIdx.z;
  int e = mt_expert[mt];
  if (e < 0) return;
  const char* Bt = (const char*)(((e < E) ? (W2T + (size_t)e * D * F) : W2sT)
                                 + (size_t)ntile * (F / 32) * 4096);
  const char* At = (const char*)(Hb + (size_t)mt * (F / 32) * 4096);
  O += (size_t)kz * NROWS * D;
  __shared__ unsigned short Al[2][128 * 32];
  __shared__ unsigned short Bl[2][128 * 32];
  int tid = threadIdx.x;
  int lane = tid & 63, wv = tid >> 6, wm = wv >> 1, wn = wv & 1;
  int row16 = lane & 15, quad = lane >> 4;
  int qsw8 = (quad ^ ((lane >> 1) & 3)) * 8;
  int swzb = (tid >> 2) * 64 + (((tid & 3) ^ ((tid >> 3) & 3)) * 16);
  int lw = wv * 1024;
  floatx4 acc[4][4];
#pragma unroll
  for (int i = 0; i < 4; ++i)
#pragma unroll
    for (int j = 0; j < 4; ++j) acc[i][j] = (floatx4){0.f, 0.f, 0.f, 0.f};

  auto stage = [&](int kt, int b) {
    size_t o = (size_t)kt * 8192;
    glds16(At + o + swzb, (char*)Al[b] + lw);
    glds16(At + o + 4096 + swzb, (char*)Al[b] + 4096 + lw);
    glds16(Bt + o + swzb, (char*)Bl[b] + lw);
    glds16(Bt + o + 4096 + swzb, (char*)Bl[b] + 4096 + lw);
  };

  int k0 = kz * 64, kend = k0 + 64;
  stage(k0, 0);
  __syncthreads();
  int cur = 0;
  for (int kt = k0; kt < kend; ++kt) {
    if (kt + 1 < kend) stage(kt + 1, cur ^ 1);
    const unsigned short* Ac = Al[cur];
    const unsigned short* Bc = Bl[cur];
    short8 af[4], bf[4];
#pragma unroll
    for (int mi = 0; mi < 4; ++mi)
      af[mi] = *(const short8*)(Ac + (wm * 64 + mi * 16 + row16) * 32 + qsw8);
#pragma unroll
    for (int ni = 0; ni < 4; ++ni)
      bf[ni] = *(const short8*)(Bc + (wn * 64 + ni * 16 + row16) * 32 + qsw8);
#pragma unroll
    for (int mi = 0; mi < 4; ++mi)
#pragma unroll
      for (int ni = 0; ni < 4; ++ni)
        acc[mi][ni] = __builtin_amdgcn_mfma_f32_16x16x32_bf16(af[mi], bf[ni], acc[mi][ni], 0, 0, 0);
    __syncthreads();
    cur ^= 1;
  }
#pragma unroll
  for (int mi = 0; mi < 4; ++mi)
#pragma unroll
    for (int ni = 0; ni < 4; ++ni)
#pragma unroll
      for (int r = 0; r < 4; ++r) {
        int grow = mt * 128 + wm * 64 + mi * 16 + quad * 4 + r;
        int col = ntile * 128 + wn * 64 + ni * 16 + row16;
        float scale = (grow < SHB) ? row_scale[grow] : 0.0625f;
        O[(size_t)grow * D + col] = acc[mi][ni][r] * scale;
      }
}

// ---------------- combine: out = sum over {r0, r1, shared} x {2 k-halves} ----------------
__global__ void combine_kernel(const float* __restrict__ O, const int* __restrict__ tok_rows,
                               float* __restrict__ out) {
  int idx = blockIdx.x * 256 + threadIdx.x;  // T * D/4
  int t = idx >> 8, c = idx & 255;
  int r0 = tok_rows[2 * t], r1 = tok_rows[2 * t + 1];
  const float4* O4 = (const float4*)O;
  const size_t HLF = (size_t)NROWS * 256;
  float4 a = O4[(size_t)r0 * 256 + c];
  float4 b = O4[(size_t)r1 * 256 + c];
  float4 s = O4[((size_t)SHB + t) * 256 + c];
  float4 a2 = O4[HLF + (size_t)r0 * 256 + c];
  float4 b2 = O4[HLF + (size_t)r1 * 256 + c];
  float4 s2 = O4[HLF + ((size_t)SHB + t) * 256 + c];
  float4 r;
  r.x = a.x + b.x + s.x + a2.x + b2.x + s2.x;
  r.y = a.y + b.y + s.y + a2.y + b2.y + s2.y;
  r.z = a.z + b.z + s.z + a2.z + b2.z + s2.z;
  r.w = a.w + b.w + s.w + a2.w + b2.w + s2.w;
  ((float4*)out)[idx] = r;
}

extern "C" void kernel_launch(void* const* d_in, const int* in_sizes, int n_in,
                              void* d_out, int out_size, void* d_ws, size_t ws_size,
                              hipStream_t stream) {
  (void)in_sizes; (void)n_in; (void)out_size; (void)ws_size;
  const float* x   = (const float*)d_in[0];
  const float* gW  = (const float*)d_in[1];
  const float* w1e = (const float*)d_in[2];
  const float* w3e = (const float*)d_in[3];
  const float* w2e = (const float*)d_in[4];
  const float* w1s = (const float*)d_in[5];
  const float* w3s = (const float*)d_in[6];
  const float* w2s = (const float*)d_in[7];
  float* out = (float*)d_out;

  char* w = (char*)d_ws;
  auto alloc = [&](size_t bytes) {
    char* p = w; w += (bytes + 255) & ~(size_t)255; return p;
  };
  unsigned short* xb   = (unsigned short*)alloc((size_t)T * D * 2);
  unsigned short* W1T  = (unsigned short*)alloc((size_t)E * F * D * 2);
  unsigned short* W3T  = (unsigned short*)alloc((size_t)E * F * D * 2);
  unsigned short* W2T  = (unsigned short*)alloc((size_t)E * D * F * 2);
  unsigned short* W1sT = (unsigned short*)alloc((size_t)F * D * 2);
  unsigned short* W3sT = (unsigned short*)alloc((size_t)F * D * 2);
  unsigned short* W2sT = (unsigned short*)alloc((size_t)D * F * 2);
  unsigned short* Hb   = (unsigned short*)alloc((size_t)NROWS * F * 2);
  float* Ob        = (float*)alloc((size_t)2 * NROWS * D * 4);
  float* row_scale = (float*)alloc((size_t)SHB * 4);
  float* list_gate = (float*)alloc((size_t)E * T * 4);
  int* list_tok    = (int*)alloc((size_t)E * T * 4);
  int* tok_rows    = (int*)alloc((size_t)T * 2 * 4);
  int* offv        = (int*)alloc(16 * 4);
  int* mt_expert   = (int*)alloc(64 * 4);
  int* ctrl        = (int*)alloc((size_t)(8 + T + SHB) * 4);
  int* cnt = ctrl; int* tk = ctrl + 8; int* tok_of_row = ctrl + 8 + T;

  hipMemsetAsync(ctrl, 0, (size_t)(8 + T + SHB) * 4, stream);
  gate_kernel<<<T, 256, 0, stream>>>(x, gW, xb, cnt, list_tok, list_gate);
  offsets_kernel<<<1, 64, 0, stream>>>(cnt, offv, mt_expert);
  scatter_kernel<<<(E * T) / 256, 256, 0, stream>>>(cnt, offv, list_tok, list_gate,
                                                    tok_of_row, row_scale, tok_rows, tk);
  transpose_cast<<<dim3(F / 32, D / 32, E), 256, 0, stream>>>(w1e, W1T, D, F);
  transpose_cast<<<dim3(F / 32, D / 32, E), 256, 0, stream>>>(w3e, W3T, D, F);
  transpose_cast<<<dim3(D / 32, F / 32, E), 256, 0, stream>>>(w2e, W2T, F, D);
  transpose_cast<<<dim3(FS / 32, D / 32, NS), 256, 0, stream>>>(w1s, W1sT, D, FS);
  transpose_cast<<<dim3(FS / 32, D / 32, NS), 256, 0, stream>>>(w3s, W3sT, D, FS);
  transpose_cast<<<dim3(D / 32, F / 32, 1), 256, 0, stream>>>(w2s, W2sT, F, D);
  up_gemm<<<dim3(F / 128, MT_MAX), 256, 0, stream>>>(xb, W1T, W3T, W1sT, W3sT,
                                                     mt_expert, tok_of_row, Hb);
  down_gemm<<<dim3(D / 128, MT_MAX, 2), 256, 0, stream>>>(Hb, W2T, W2sT, mt_expert, row_scale, Ob);
  combine_kernel<<<(T * D / 4) / 256, 256, 0, stream>>>(Ob, tok_rows, out);
}

// Round 2
// 726.865 us; speedup vs baseline: 1.0573x; 1.0573x over previous
//
#include <hip/hip_runtime.h>

#define T 2048
#define D 1024
#define F 4096
#define E 8
#define NS 8
#define FS 512
#define SHB 5120      // shared-expert H base row (routed padded capacity)
#define NROWS 7168    // SHB + T
#define MT_MAX 56     // NROWS/128

typedef float floatx4 __attribute__((ext_vector_type(4)));
typedef short short8 __attribute__((ext_vector_type(8)));

__device__ __forceinline__ unsigned short f2bf(float f) {
  unsigned int u = __float_as_uint(f);
  u += 0x7FFF + ((u >> 16) & 1);   // RNE
  return (unsigned short)(u >> 16);
}

__device__ __forceinline__ void glds16(const void* g, void* l) {
  __builtin_amdgcn_global_load_lds(
      (const __attribute__((address_space(1))) void*)g,
      (__attribute__((address_space(3))) void*)l, 16, 0, 0);
}

// ---------------- gate: logits, softmax, top-2, x -> bf16 ----------------
__global__ void gate_kernel(const float* __restrict__ x, const float* __restrict__ gW,
                            unsigned short* __restrict__ xb, int* __restrict__ cnt,
                            int* __restrict__ list_tok, float* __restrict__ list_gate) {
  int t = blockIdx.x, tid = threadIdx.x;
  const float* xr = x + (size_t)t * D;
  float acc[E];
#pragma unroll
  for (int e = 0; e < E; ++e) acc[e] = 0.f;
  for (int d = tid; d < D; d += 256) {
    float xv = xr[d];
    xb[(size_t)t * D + d] = f2bf(xv);
#pragma unroll
    for (int e = 0; e < E; ++e) acc[e] += xv * gW[e * D + d];
  }
#pragma unroll
  for (int o = 32; o > 0; o >>= 1)
#pragma unroll
    for (int e = 0; e < E; ++e) acc[e] += __shfl_down(acc[e], o, 64);
  __shared__ float wred[4][E];
  int lane = tid & 63, wv = tid >> 6;
  if (lane == 0)
#pragma unroll
    for (int e = 0; e < E; ++e) wred[wv][e] = acc[e];
  __syncthreads();
  if (tid == 0) {
    float l[E];
#pragma unroll
    for (int e = 0; e < E; ++e) l[e] = wred[0][e] + wred[1][e] + wred[2][e] + wred[3][e];
    int i1 = 0; float m1 = l[0];
    for (int e = 1; e < E; ++e) if (l[e] > m1) { m1 = l[e]; i1 = e; }
    int i2 = -1; float m2 = -3.4e38f;
    for (int e = 0; e < E; ++e) if (e != i1 && l[e] > m2) { m2 = l[e]; i2 = e; }
    float s = 0.f, p[E];
#pragma unroll
    for (int e = 0; e < E; ++e) { p[e] = __expf(l[e] - m1); s += p[e]; }
    float inv = 1.f / s;
    int p1 = atomicAdd(&cnt[i1], 1);
    list_tok[i1 * T + p1] = t; list_gate[i1 * T + p1] = p[i1] * inv;
    int p2 = atomicAdd(&cnt[i2], 1);
    list_tok[i2 * T + p2] = t; list_gate[i2 * T + p2] = p[i2] * inv;
  }
}

// ---------------- offsets (1 thread): 128-aligned segment starts ----------------
__global__ void offsets_kernel(const int* __restrict__ cnt, int* __restrict__ off,
                               int* __restrict__ mt_expert) {
  if (threadIdx.x == 0 && blockIdx.x == 0) {
    int o = 0;
    for (int e = 0; e < E; ++e) { off[e] = o; o += (cnt[e] + 127) & ~127; }
    off[E] = o;
    for (int i = 0; i < MT_MAX; ++i) mt_expert[i] = -1;
    for (int e = 0; e < E; ++e) {
      int t0 = off[e] >> 7, nt = (cnt[e] + 127) >> 7;
      for (int i = 0; i < nt; ++i) mt_expert[t0 + i] = e;
    }
    for (int i = SHB >> 7; i < MT_MAX; ++i) mt_expert[i] = E;
  }
}

// ---------------- scatter: row maps + per-row scales ----------------
__global__ void scatter_kernel(const int* __restrict__ cnt, const int* __restrict__ off,
                               const int* __restrict__ list_tok, const float* __restrict__ list_gate,
                               int* __restrict__ tok_of_row, float* __restrict__ row_scale,
                               int* __restrict__ tok_rows, int* __restrict__ tk) {
  int idx = blockIdx.x * 256 + threadIdx.x;  // E*T
  int e = idx >> 11, i = idx & (T - 1);
  if (e < E && i < cnt[e]) {
    int row = off[e] + i;
    int t = list_tok[e * T + i];
    tok_of_row[row] = t;
    row_scale[row] = 0.5f * list_gate[e * T + i];
    int k = atomicAdd(&tk[t], 1);
    tok_rows[2 * t + k] = row;
  }
}

// ------- transpose+cast fp32 [R,C] -> bf16 B^T tiled [C/128][R/32][128][32] -------
// 32r x 32c tile, 256 threads: 1 float4 read pass + 1 ushort4 write pass
__global__ void transpose_cast(const float* __restrict__ in, unsigned short* __restrict__ out,
                               int R, int C) {
  in += (size_t)blockIdx.z * R * C;
  out += (size_t)blockIdx.z * R * C;
  int r0 = blockIdx.y * 32, c0 = blockIdx.x * 32;
  __shared__ float tile[32][33];
  int tid = threadIdx.x;
  {
    int rl = tid >> 3, cl = (tid & 7) * 4;
    float4 v = *(const float4*)(in + (size_t)(r0 + rl) * C + c0 + cl);
    tile[rl][cl] = v.x; tile[rl][cl + 1] = v.y;
    tile[rl][cl + 2] = v.z; tile[rl][cl + 3] = v.w;
  }
  __syncthreads();
  {
    int cl = tid >> 3, rq = (tid & 7) * 4;
    int c = c0 + cl, r = r0 + rq;
    ushort4 v;
    v.x = f2bf(tile[rq][cl]);     v.y = f2bf(tile[rq + 1][cl]);
    v.z = f2bf(tile[rq + 2][cl]); v.w = f2bf(tile[rq + 3][cl]);
    int Rt = R >> 5;
    size_t o = ((size_t)(c >> 7) * Rt + (r >> 5)) * 4096 + (size_t)(c & 127) * 32 + (r & 31);
    *(ushort4*)(out + o) = v;
  }
}

// ---------------- up GEMM: H = silu(A@W1) * (A@W3), grouped by expert ----------------
// 2-phase double-buffered with STATIC ping-pong buffers (named __shared__ arrays,
// K-loop unrolled x2) so the LDS alias analyzer can prove glds(next buf) does not
// alias ds_read(cur buf) -> the prefetch stays in flight across the MFMA phase.
// LDS XOR-swizzle: 16B slot j of row r holds global slot j ^ ((r>>1)&3).
__global__ __launch_bounds__(256, 2) void up_gemm(
    const unsigned short* __restrict__ xb, const unsigned short* __restrict__ W1T,
    const unsigned short* __restrict__ W3T, const unsigned short* __restrict__ W1sT,
    const unsigned short* __restrict__ W3sT, const int* __restrict__ mt_expert,
    const int* __restrict__ tok_of_row, unsigned short* __restrict__ Hb) {
  int mt = blockIdx.y, ntile = blockIdx.x;
  int e = mt_expert[mt];
  if (e < 0) return;
  const unsigned short *B1, *B3;
  if (e < E) {
    B1 = W1T + (size_t)e * F * D;
    B3 = W3T + (size_t)e * F * D;
  } else {
    B1 = W1sT; B3 = W3sT;
  }
  __shared__ unsigned short Al0[128 * 32], B1l0[128 * 32], B3l0[128 * 32];
  __shared__ unsigned short Al1[128 * 32], B1l1[128 * 32], B3l1[128 * 32];
  int tid = threadIdx.x;
  int lane = tid & 63, wv = tid >> 6, wm = wv >> 1, wn = wv & 1;
  int row16 = lane & 15, quad = lane >> 4;
  int qsw8 = (quad ^ ((lane >> 1) & 3)) * 8;   // swizzled read slot, in shorts
  int swzb = (tid >> 2) * 64 + (((tid & 3) ^ ((tid >> 3) & 3)) * 16);  // staging src byte off
  int lw = wv * 1024;  // wave LDS byte offset (glds dest must be wave-uniform)

  // A gather: thread stages row r1 = tid>>2 (call 1) and r1+64 (call 2), 16B slot
  // (tid&3) ^ sa(row); sa(row) = (row>>1)&3 = (tid>>3)&3 for BOTH rows (64 even).
  int r1 = tid >> 2;
  int hrow1 = mt * 128 + r1, hrow2 = hrow1 + 64;
  int srow1 = (e < E) ? tok_of_row[hrow1] : (hrow1 - SHB);
  int srow2 = (e < E) ? tok_of_row[hrow2] : (hrow2 - SHB);
  int asl = ((tid & 3) ^ ((tid >> 3) & 3)) * 16;
  const char* asrc1 = (const char*)(xb + (size_t)srow1 * D) + asl;
  const char* asrc2 = (const char*)(xb + (size_t)srow2 * D) + asl;
  const char* b1t = (const char*)(B1 + (size_t)ntile * (D / 32) * 4096);
  const char* b3t = (const char*)(B3 + (size_t)ntile * (D / 32) * 4096);

  floatx4 accg[4][4], accu[4][4];
#pragma unroll
  for (int i = 0; i < 4; ++i)
#pragma unroll
    for (int j = 0; j < 4; ++j) {
      accg[i][j] = (floatx4){0.f, 0.f, 0.f, 0.f};
      accu[i][j] = (floatx4){0.f, 0.f, 0.f, 0.f};
    }

  auto stage = [&](int kt, unsigned short* Ad, unsigned short* B1d, unsigned short* B3d) {
    size_t ko = (size_t)kt * 64;     // A advances 32 bf16 = 64 B per K-step
    size_t bo = (size_t)kt * 8192;   // B tile = 8 KB per K-step
    glds16(asrc1 + ko, (char*)Ad + lw);
    glds16(asrc2 + ko, (char*)Ad + 4096 + lw);
    glds16(b1t + bo + swzb, (char*)B1d + lw);
    glds16(b1t + bo + 4096 + swzb, (char*)B1d + 4096 + lw);
    glds16(b3t + bo + swzb, (char*)B3d + lw);
    glds16(b3t + bo + 4096 + swzb, (char*)B3d + 4096 + lw);
  };
  auto compute = [&](const unsigned short* Ac, const unsigned short* B1c,
                     const unsigned short* B3c) {
    short8 af[4], b1f[4], b3f[4];
#pragma unroll
    for (int mi = 0; mi < 4; ++mi)
      af[mi] = *(const short8*)(Ac + (wm * 64 + mi * 16 + row16) * 32 + qsw8);
#pragma unroll
    for (int ni = 0; ni < 4; ++ni) {
      b1f[ni] = *(const short8*)(B1c + (wn * 64 + ni * 16 + row16) * 32 + qsw8);
      b3f[ni] = *(const short8*)(B3c + (wn * 64 + ni * 16 + row16) * 32 + qsw8);
    }
#pragma unroll
    for (int mi = 0; mi < 4; ++mi)
#pragma unroll
      for (int ni = 0; ni < 4; ++ni) {
        accg[mi][ni] = __builtin_amdgcn_mfma_f32_16x16x32_bf16(af[mi], b1f[ni], accg[mi][ni], 0, 0, 0);
        accu[mi][ni] = __builtin_amdgcn_mfma_f32_16x16x32_bf16(af[mi], b3f[ni], accu[mi][ni], 0, 0, 0);
      }
  };

  stage(0, Al0, B1l0, B3l0);
  __syncthreads();
  // D/32 = 32 K-steps; unrolled x2 with peeled tail (static buffer identity).
  for (int kt = 0; kt < D / 32 - 2; kt += 2) {
    stage(kt + 1, Al1, B1l1, B3l1);   // prefetch odd tile, in flight during MFMA
    compute(Al0, B1l0, B3l0);         // tile kt
    __syncthreads();
    stage(kt + 2, Al0, B1l0, B3l0);   // prefetch even tile
    compute(Al1, B1l1, B3l1);         // tile kt+1
    __syncthreads();
  }
  stage(D / 32 - 1, Al1, B1l1, B3l1);
  compute(Al0, B1l0, B3l0);           // tile 30
  __syncthreads();
  compute(Al1, B1l1, B3l1);           // tile 31

  // epilogue: silu(g)*u -> bf16, H in tiled layout
#pragma unroll
  for (int mi = 0; mi < 4; ++mi)
#pragma unroll
    for (int ni = 0; ni < 4; ++ni)
#pragma unroll
      for (int r = 0; r < 4; ++r) {
        int hrow = mt * 128 + wm * 64 + mi * 16 + quad * 4 + r;
        int col = ntile * 128 + wn * 64 + ni * 16 + row16;
        float g = accg[mi][ni][r], u = accu[mi][ni][r];
        float h = g * u / (1.0f + __expf(-g));
        size_t o = ((size_t)(hrow >> 7) * 128 + (col >> 5)) * 4096 + (size_t)(hrow & 127) * 32 + (col & 31);
        Hb[o] = f2bf(h);
      }
}

// ---------------- down GEMM: O = (H @ W2) * row_scale, split-K x2 ----------------
// Same static 2-phase double-buffered schedule.
__global__ __launch_bounds__(256, 2) void down_gemm(
    const unsigned short* __restrict__ Hb, const unsigned short* __restrict__ W2T,
    const unsigned short* __restrict__ W2sT, const int* __restrict__ mt_expert,
    const float* __restrict__ row_scale, float* __restrict__ O) {
  int mt = blockIdx.y, ntile = blockIdx.x, kz = blockIdx.z;
  int e = mt_expert[mt];
  if (e < 0) return;
  const char* Bt = (const char*)(((e < E) ? (W2T + (size_t)e * D * F) : W2sT)
                                 + (size_t)ntile * (F / 32) * 4096);
  const char* At = (const char*)(Hb + (size_t)mt * (F / 32) * 4096);
  O += (size_t)kz * NROWS * D;
  __shared__ unsigned short Al0[128 * 32], Bl0[128 * 32];
  __shared__ unsigned short Al1[128 * 32], Bl1[128 * 32];
  int tid = threadIdx.x;
  int lane = tid & 63, wv = tid >> 6, wm = wv >> 1, wn = wv & 1;
  int row16 = lane & 15, quad = lane >> 4;
  int qsw8 = (quad ^ ((lane >> 1) & 3)) * 8;
  int swzb = (tid >> 2) * 64 + (((tid & 3) ^ ((tid >> 3) & 3)) * 16);
  int lw = wv * 1024;
  floatx4 acc[4][4];
#pragma unroll
  for (int i = 0; i < 4; ++i)
#pragma unroll
    for (int j = 0; j < 4; ++j) acc[i][j] = (floatx4){0.f, 0.f, 0.f, 0.f};

  auto stage = [&](int kt, unsigned short* Ad, unsigned short* Bd) {
    size_t o = (size_t)kt * 8192;
    glds16(At + o + swzb, (char*)Ad + lw);
    glds16(At + o + 4096 + swzb, (char*)Ad + 4096 + lw);
    glds16(Bt + o + swzb, (char*)Bd + lw);
    glds16(Bt + o + 4096 + swzb, (char*)Bd + 4096 + lw);
  };
  auto compute = [&](const unsigned short* Ac, const unsigned short* Bc) {
    short8 af[4], bf[4];
#pragma unroll
    for (int mi = 0; mi < 4; ++mi)
      af[mi] = *(const short8*)(Ac + (wm * 64 + mi * 16 + row16) * 32 + qsw8);
#pragma unroll
    for (int ni = 0; ni < 4; ++ni)
      bf[ni] = *(const short8*)(Bc + (wn * 64 + ni * 16 + row16) * 32 + qsw8);
#pragma unroll
    for (int mi = 0; mi < 4; ++mi)
#pragma unroll
      for (int ni = 0; ni < 4; ++ni)
        acc[mi][ni] = __builtin_amdgcn_mfma_f32_16x16x32_bf16(af[mi], bf[ni], acc[mi][ni], 0, 0, 0);
  };

  int k0 = kz * 64;
  stage(k0, Al0, Bl0);
  __syncthreads();
  // 64 K-steps; unrolled x2 with peeled tail.
  for (int kt = k0; kt < k0 + 62; kt += 2) {
    stage(kt + 1, Al1, Bl1);
    compute(Al0, Bl0);
    __syncthreads();
    stage(kt + 2, Al0, Bl0);
    compute(Al1, Bl1);
    __syncthreads();
  }
  stage(k0 + 63, Al1, Bl1);
  compute(Al0, Bl0);
  __syncthreads();
  compute(Al1, Bl1);

#pragma unroll
  for (int mi = 0; mi < 4; ++mi)
#pragma unroll
    for (int ni = 0; ni < 4; ++ni)
#pragma unroll
      for (int r = 0; r < 4; ++r) {
        int grow = mt * 128 + wm * 64 + mi * 16 + quad * 4 + r;
        int col = ntile * 128 + wn * 64 + ni * 16 + row16;
        float scale = (grow < SHB) ? row_scale[grow] : 0.0625f;
        O[(size_t)grow * D + col] = acc[mi][ni][r] * scale;
      }
}

// ---------------- combine: out = sum over {r0, r1, shared} x {2 k-halves} ----------------
__global__ void combine_kernel(const float* __restrict__ O, const int* __restrict__ tok_rows,
                               float* __restrict__ out) {
  int idx = blockIdx.x * 256 + threadIdx.x;  // T * D/4
  int t = idx >> 8, c = idx & 255;
  int r0 = tok_rows[2 * t], r1 = tok_rows[2 * t + 1];
  const float4* O4 = (const float4*)O;
  const size_t HLF = (size_t)NROWS * 256;
  float4 a = O4[(size_t)r0 * 256 + c];
  float4 b = O4[(size_t)r1 * 256 + c];
  float4 s = O4[((size_t)SHB + t) * 256 + c];
  float4 a2 = O4[HLF + (size_t)r0 * 256 + c];
  float4 b2 = O4[HLF + (size_t)r1 * 256 + c];
  float4 s2 = O4[HLF + ((size_t)SHB + t) * 256 + c];
  float4 r;
  r.x = a.x + b.x + s.x + a2.x + b2.x + s2.x;
  r.y = a.y + b.y + s.y + a2.y + b2.y + s2.y;
  r.z = a.z + b.z + s.z + a2.z + b2.z + s2.z;
  r.w = a.w + b.w + s.w + a2.w + b2.w + s2.w;
  ((float4*)out)[idx] = r;
}

extern "C" void kernel_launch(void* const* d_in, const int* in_sizes, int n_in,
                              void* d_out, int out_size, void* d_ws, size_t ws_size,
                              hipStream_t stream) {
  (void)in_sizes; (void)n_in; (void)out_size; (void)ws_size;
  const float* x   = (const float*)d_in[0];
  const float* gW  = (const float*)d_in[1];
  const float* w1e = (const float*)d_in[2];
  const float* w3e = (const float*)d_in[3];
  const float* w2e = (const float*)d_in[4];
  const float* w1s = (const float*)d_in[5];
  const float* w3s = (const float*)d_in[6];
  const float* w2s = (const float*)d_in[7];
  float* out = (float*)d_out;

  char* w = (char*)d_ws;
  auto alloc = [&](size_t bytes) {
    char* p = w; w += (bytes + 255) & ~(size_t)255; return p;
  };
  unsigned short* xb   = (unsigned short*)alloc((size_t)T * D * 2);
  unsigned short* W1T  = (unsigned short*)alloc((size_t)E * F * D * 2);
  unsigned short* W3T  = (unsigned short*)alloc((size_t)E * F * D * 2);
  unsigned short* W2T  = (unsigned short*)alloc((size_t)E * D * F * 2);
  unsigned short* W1sT = (unsigned short*)alloc((size_t)F * D * 2);
  unsigned short* W3sT = (unsigned short*)alloc((size_t)F * D * 2);
  unsigned short* W2sT = (unsigned short*)alloc((size_t)D * F * 2);
  unsigned short* Hb   = (unsigned short*)alloc((size_t)NROWS * F * 2);
  float* Ob        = (float*)alloc((size_t)2 * NROWS * D * 4);
  float* row_scale = (float*)alloc((size_t)SHB * 4);
  float* list_gate = (float*)alloc((size_t)E * T * 4);
  int* list_tok    = (int*)alloc((size_t)E * T * 4);
  int* tok_rows    = (int*)alloc((size_t)T * 2 * 4);
  int* offv        = (int*)alloc(16 * 4);
  int* mt_expert   = (int*)alloc(64 * 4);
  int* ctrl        = (int*)alloc((size_t)(8 + T + SHB) * 4);
  int* cnt = ctrl; int* tk = ctrl + 8; int* tok_of_row = ctrl + 8 + T;

  hipMemsetAsync(ctrl, 0, (size_t)(8 + T + SHB) * 4, stream);
  gate_kernel<<<T, 256, 0, stream>>>(x, gW, xb, cnt, list_tok, list_gate);
  offsets_kernel<<<1, 64, 0, stream>>>(cnt, offv, mt_expert);
  scatter_kernel<<<(E * T) / 256, 256, 0, stream>>>(cnt, offv, list_tok, list_gate,
                                                    tok_of_row, row_scale, tok_rows, tk);
  transpose_cast<<<dim3(F / 32, D / 32, E), 256, 0, stream>>>(w1e, W1T, D, F);
  transpose_cast<<<dim3(F / 32, D / 32, E), 256, 0, stream>>>(w3e, W3T, D, F);
  transpose_cast<<<dim3(D / 32, F / 32, E), 256, 0, stream>>>(w2e, W2T, F, D);
  transpose_cast<<<dim3(FS / 32, D / 32, NS), 256, 0, stream>>>(w1s, W1sT, D, FS);
  transpose_cast<<<dim3(FS / 32, D / 32, NS), 256, 0, stream>>>(w3s, W3sT, D, FS);
  transpose_cast<<<dim3(D / 32, F / 32, 1), 256, 0, stream>>>(w2s, W2sT, F, D);
  up_gemm<<<dim3(F / 128, MT_MAX), 256, 0, stream>>>(xb, W1T, W3T, W1sT, W3sT,
                                                     mt_expert, tok_of_row, Hb);
  down_gemm<<<dim3(D / 128, MT_MAX, 2), 256, 0, stream>>>(Hb, W2T, W2sT, mt_expert, row_scale, Ob);
  combine_kernel<<<(T * D / 4) / 256, 256, 0, stream>>>(Ob, tok_rows, out);
}

// Round 3
// 721.879 us; speedup vs baseline: 1.0646x; 1.0069x over previous
//
#include <hip/hip_runtime.h>

#define T 2048
#define D 1024
#define F 4096
#define E 8
#define NS 8
#define FS 512
#define SHB 5120      // shared-expert H base row (routed padded capacity)
#define NROWS 7168    // SHB + T
#define MT_MAX 56     // NROWS/128

typedef float floatx4 __attribute__((ext_vector_type(4)));
typedef short short8 __attribute__((ext_vector_type(8)));

__device__ __forceinline__ unsigned short f2bf(float f) {
  unsigned int u = __float_as_uint(f);
  u += 0x7FFF + ((u >> 16) & 1);   // RNE
  return (unsigned short)(u >> 16);
}

__device__ __forceinline__ void glds16(const void* g, void* l) {
  __builtin_amdgcn_global_load_lds(
      (const __attribute__((address_space(1))) void*)g,
      (__attribute__((address_space(3))) void*)l, 16, 0, 0);
}

// ---------------- gate: logits, softmax, top-2, x -> bf16 ----------------
__global__ void gate_kernel(const float* __restrict__ x, const float* __restrict__ gW,
                            unsigned short* __restrict__ xb, int* __restrict__ cnt,
                            int* __restrict__ list_tok, float* __restrict__ list_gate) {
  int t = blockIdx.x, tid = threadIdx.x;
  const float* xr = x + (size_t)t * D;
  float acc[E];
#pragma unroll
  for (int e = 0; e < E; ++e) acc[e] = 0.f;
  for (int d = tid; d < D; d += 256) {
    float xv = xr[d];
    xb[(size_t)t * D + d] = f2bf(xv);
#pragma unroll
    for (int e = 0; e < E; ++e) acc[e] += xv * gW[e * D + d];
  }
#pragma unroll
  for (int o = 32; o > 0; o >>= 1)
#pragma unroll
    for (int e = 0; e < E; ++e) acc[e] += __shfl_down(acc[e], o, 64);
  __shared__ float wred[4][E];
  int lane = tid & 63, wv = tid >> 6;
  if (lane == 0)
#pragma unroll
    for (int e = 0; e < E; ++e) wred[wv][e] = acc[e];
  __syncthreads();
  if (tid == 0) {
    float l[E];
#pragma unroll
    for (int e = 0; e < E; ++e) l[e] = wred[0][e] + wred[1][e] + wred[2][e] + wred[3][e];
    int i1 = 0; float m1 = l[0];
    for (int e = 1; e < E; ++e) if (l[e] > m1) { m1 = l[e]; i1 = e; }
    int i2 = -1; float m2 = -3.4e38f;
    for (int e = 0; e < E; ++e) if (e != i1 && l[e] > m2) { m2 = l[e]; i2 = e; }
    float s = 0.f, p[E];
#pragma unroll
    for (int e = 0; e < E; ++e) { p[e] = __expf(l[e] - m1); s += p[e]; }
    float inv = 1.f / s;
    int p1 = atomicAdd(&cnt[i1], 1);
    list_tok[i1 * T + p1] = t; list_gate[i1 * T + p1] = p[i1] * inv;
    int p2 = atomicAdd(&cnt[i2], 1);
    list_tok[i2 * T + p2] = t; list_gate[i2 * T + p2] = p[i2] * inv;
  }
}

// ---------------- offsets (1 thread): 128-aligned segment starts ----------------
__global__ void offsets_kernel(const int* __restrict__ cnt, int* __restrict__ off,
                               int* __restrict__ mt_expert) {
  if (threadIdx.x == 0 && blockIdx.x == 0) {
    int o = 0;
    for (int e = 0; e < E; ++e) { off[e] = o; o += (cnt[e] + 127) & ~127; }
    off[E] = o;
    for (int i = 0; i < MT_MAX; ++i) mt_expert[i] = -1;
    for (int e = 0; e < E; ++e) {
      int t0 = off[e] >> 7, nt = (cnt[e] + 127) >> 7;
      for (int i = 0; i < nt; ++i) mt_expert[t0 + i] = e;
    }
    for (int i = SHB >> 7; i < MT_MAX; ++i) mt_expert[i] = E;
  }
}

// ---------------- scatter: row maps + per-row scales ----------------
__global__ void scatter_kernel(const int* __restrict__ cnt, const int* __restrict__ off,
                               const int* __restrict__ list_tok, const float* __restrict__ list_gate,
                               int* __restrict__ tok_of_row, float* __restrict__ row_scale,
                               int* __restrict__ tok_rows, int* __restrict__ tk) {
  int idx = blockIdx.x * 256 + threadIdx.x;  // E*T
  int e = idx >> 11, i = idx & (T - 1);
  if (e < E && i < cnt[e]) {
    int row = off[e] + i;
    int t = list_tok[e * T + i];
    tok_of_row[row] = t;
    row_scale[row] = 0.5f * list_gate[e * T + i];
    int k = atomicAdd(&tk[t], 1);
    tok_rows[2 * t + k] = row;
  }
}

// ------- transpose+cast fp32 [R,C] -> bf16 B^T tiled [C/128][R/32][128][32] -------
// 32r x 32c tile, 256 threads: 1 float4 read pass + 1 ushort4 write pass
__global__ void transpose_cast(const float* __restrict__ in, unsigned short* __restrict__ out,
                               int R, int C) {
  in += (size_t)blockIdx.z * R * C;
  out += (size_t)blockIdx.z * R * C;
  int r0 = blockIdx.y * 32, c0 = blockIdx.x * 32;
  __shared__ float tile[32][33];
  int tid = threadIdx.x;
  {
    int rl = tid >> 3, cl = (tid & 7) * 4;
    float4 v = *(const float4*)(in + (size_t)(r0 + rl) * C + c0 + cl);
    tile[rl][cl] = v.x; tile[rl][cl + 1] = v.y;
    tile[rl][cl + 2] = v.z; tile[rl][cl + 3] = v.w;
  }
  __syncthreads();
  {
    int cl = tid >> 3, rq = (tid & 7) * 4;
    int c = c0 + cl, r = r0 + rq;
    ushort4 v;
    v.x = f2bf(tile[rq][cl]);     v.y = f2bf(tile[rq + 1][cl]);
    v.z = f2bf(tile[rq + 2][cl]); v.w = f2bf(tile[rq + 3][cl]);
    int Rt = R >> 5;
    size_t o = ((size_t)(c >> 7) * Rt + (r >> 5)) * 4096 + (size_t)(c & 127) * 32 + (r & 31);
    *(ushort4*)(out + o) = v;
  }
}

// ---------------- up GEMM: H = silu(A@W1) * (A@W3), grouped by expert ----------------
// Depth-2 pipeline (T4 counted-vmcnt): 3 static LDS buffers, raw s_barrier, manual
// s_waitcnt vmcnt(6) (= one stage's glds count) so a full stage stays in flight
// across each barrier. Iteration: [stage(t+2); compute(t); vmcnt(6); s_barrier].
//   RAW: end-of-iter vmcnt forces stage(t+1) complete before the barrier -> all
//        waves see it before any compute(t+1).
//   WAR: stage(t+2) reuses buf[(t-1)%3]; its readers finished before the previous
//        barrier (ds_reads consumed by MFMAs issued pre-barrier).
// LDS XOR-swizzle: 16B slot j of row r holds global slot j ^ ((r>>1)&3).
__global__ __launch_bounds__(256, 2) void up_gemm(
    const unsigned short* __restrict__ xb, const unsigned short* __restrict__ W1T,
    const unsigned short* __restrict__ W3T, const unsigned short* __restrict__ W1sT,
    const unsigned short* __restrict__ W3sT, const int* __restrict__ mt_expert,
    const int* __restrict__ tok_of_row, unsigned short* __restrict__ Hb) {
  int mt = blockIdx.y, ntile = blockIdx.x;
  int e = mt_expert[mt];
  if (e < 0) return;
  const unsigned short *B1, *B3;
  if (e < E) {
    B1 = W1T + (size_t)e * F * D;
    B3 = W3T + (size_t)e * F * D;
  } else {
    B1 = W1sT; B3 = W3sT;
  }
  __shared__ unsigned short Au0[128 * 32], B1u0[128 * 32], B3u0[128 * 32];
  __shared__ unsigned short Au1[128 * 32], B1u1[128 * 32], B3u1[128 * 32];
  __shared__ unsigned short Au2[128 * 32], B1u2[128 * 32], B3u2[128 * 32];
  int tid = threadIdx.x;
  int lane = tid & 63, wv = tid >> 6, wm = wv >> 1, wn = wv & 1;
  int row16 = lane & 15, quad = lane >> 4;
  int qsw8 = (quad ^ ((lane >> 1) & 3)) * 8;   // swizzled read slot, in shorts
  int swzb = (tid >> 2) * 64 + (((tid & 3) ^ ((tid >> 3) & 3)) * 16);  // staging src byte off
  int lw = wv * 1024;  // wave LDS byte offset (glds dest must be wave-uniform)

  // A gather: thread stages row r1 = tid>>2 (call 1) and r1+64 (call 2), 16B slot
  // (tid&3) ^ sa(row); sa(row) = (row>>1)&3 = (tid>>3)&3 for BOTH rows (64 even).
  int r1 = tid >> 2;
  int hrow1 = mt * 128 + r1, hrow2 = hrow1 + 64;
  int srow1 = (e < E) ? tok_of_row[hrow1] : (hrow1 - SHB);
  int srow2 = (e < E) ? tok_of_row[hrow2] : (hrow2 - SHB);
  int asl = ((tid & 3) ^ ((tid >> 3) & 3)) * 16;
  const char* asrc1 = (const char*)(xb + (size_t)srow1 * D) + asl;
  const char* asrc2 = (const char*)(xb + (size_t)srow2 * D) + asl;
  const char* b1t = (const char*)(B1 + (size_t)ntile * (D / 32) * 4096);
  const char* b3t = (const char*)(B3 + (size_t)ntile * (D / 32) * 4096);

  floatx4 accg[4][4], accu[4][4];
#pragma unroll
  for (int i = 0; i < 4; ++i)
#pragma unroll
    for (int j = 0; j < 4; ++j) {
      accg[i][j] = (floatx4){0.f, 0.f, 0.f, 0.f};
      accu[i][j] = (floatx4){0.f, 0.f, 0.f, 0.f};
    }

  auto stage = [&](int kt, unsigned short* Ad, unsigned short* B1d, unsigned short* B3d) {
    size_t ko = (size_t)kt * 64;     // A advances 32 bf16 = 64 B per K-step
    size_t bo = (size_t)kt * 8192;   // B tile = 8 KB per K-step
    glds16(asrc1 + ko, (char*)Ad + lw);
    glds16(asrc2 + ko, (char*)Ad + 4096 + lw);
    glds16(b1t + bo + swzb, (char*)B1d + lw);
    glds16(b1t + bo + 4096 + swzb, (char*)B1d + 4096 + lw);
    glds16(b3t + bo + swzb, (char*)B3d + lw);
    glds16(b3t + bo + 4096 + swzb, (char*)B3d + 4096 + lw);
  };
  auto compute = [&](const unsigned short* Ac, const unsigned short* B1c,
                     const unsigned short* B3c) {
    short8 af[4], b1f[4], b3f[4];
#pragma unroll
    for (int mi = 0; mi < 4; ++mi)
      af[mi] = *(const short8*)(Ac + (wm * 64 + mi * 16 + row16) * 32 + qsw8);
#pragma unroll
    for (int ni = 0; ni < 4; ++ni) {
      b1f[ni] = *(const short8*)(B1c + (wn * 64 + ni * 16 + row16) * 32 + qsw8);
      b3f[ni] = *(const short8*)(B3c + (wn * 64 + ni * 16 + row16) * 32 + qsw8);
    }
#pragma unroll
    for (int mi = 0; mi < 4; ++mi)
#pragma unroll
      for (int ni = 0; ni < 4; ++ni) {
        accg[mi][ni] = __builtin_amdgcn_mfma_f32_16x16x32_bf16(af[mi], b1f[ni], accg[mi][ni], 0, 0, 0);
        accu[mi][ni] = __builtin_amdgcn_mfma_f32_16x16x32_bf16(af[mi], b3f[ni], accu[mi][ni], 0, 0, 0);
      }
  };

  stage(0, Au0, B1u0, B3u0);
  stage(1, Au1, B1u1, B3u1);
  asm volatile("s_waitcnt vmcnt(6)" ::: "memory");   // stage(0) landed
  __builtin_amdgcn_s_barrier();
  // 32 K-steps: iters 0..29 stage t+2 (3-unrolled for static buffer identity),
  // then two drain iterations.
  for (int t = 0; t < 30; t += 3) {
    stage(t + 2, Au2, B1u2, B3u2);
    compute(Au0, B1u0, B3u0);
    asm volatile("s_waitcnt vmcnt(6)" ::: "memory");
    __builtin_amdgcn_s_barrier();
    stage(t + 3, Au0, B1u0, B3u0);
    compute(Au1, B1u1, B3u1);
    asm volatile("s_waitcnt vmcnt(6)" ::: "memory");
    __builtin_amdgcn_s_barrier();
    stage(t + 4, Au1, B1u1, B3u1);
    compute(Au2, B1u2, B3u2);
    asm volatile("s_waitcnt vmcnt(6)" ::: "memory");
    __builtin_amdgcn_s_barrier();
  }
  compute(Au0, B1u0, B3u0);            // t=30
  asm volatile("s_waitcnt vmcnt(0)" ::: "memory");   // stage(31) landed
  __builtin_amdgcn_s_barrier();
  compute(Au1, B1u1, B3u1);            // t=31

  // epilogue: silu(g)*u -> bf16, H in tiled layout
#pragma unroll
  for (int mi = 0; mi < 4; ++mi)
#pragma unroll
    for (int ni = 0; ni < 4; ++ni)
#pragma unroll
      for (int r = 0; r < 4; ++r) {
        int hrow = mt * 128 + wm * 64 + mi * 16 + quad * 4 + r;
        int col = ntile * 128 + wn * 64 + ni * 16 + row16;
        float g = accg[mi][ni][r], u = accu[mi][ni][r];
        float h = g * u / (1.0f + __expf(-g));
        size_t o = ((size_t)(hrow >> 7) * 128 + (col >> 5)) * 4096 + (size_t)(hrow & 127) * 32 + (col & 31);
        Hb[o] = f2bf(h);
      }
}

// ---------------- down GEMM: O = (H @ W2) * row_scale, split-K x2 ----------------
// Same depth-2 counted-vmcnt pipeline; stage width = 4 glds -> vmcnt(4).
__global__ __launch_bounds__(256, 2) void down_gemm(
    const unsigned short* __restrict__ Hb, const unsigned short* __restrict__ W2T,
    const unsigned short* __restrict__ W2sT, const int* __restrict__ mt_expert,
    const float* __restrict__ row_scale, float* __restrict__ O) {
  int mt = blockIdx.y, ntile = blockIdx.x, kz = blockIdx.z;
  int e = mt_expert[mt];
  if (e < 0) return;
  const char* Bt = (const char*)(((e < E) ? (W2T + (size_t)e * D * F) : W2sT)
                                 + (size_t)ntile * (F / 32) * 4096);
  const char* At = (const char*)(Hb + (size_t)mt * (F / 32) * 4096);
  O += (size_t)kz * NROWS * D;
  __shared__ unsigned short Ad0[128 * 32], Bd0[128 * 32];
  __shared__ unsigned short Ad1[128 * 32], Bd1[128 * 32];
  __shared__ unsigned short Ad2[128 * 32], Bd2[128 * 32];
  int tid = threadIdx.x;
  int lane = tid & 63, wv = tid >> 6, wm = wv >> 1, wn = wv & 1;
  int row16 = lane & 15, quad = lane >> 4;
  int qsw8 = (quad ^ ((lane >> 1) & 3)) * 8;
  int swzb = (tid >> 2) * 64 + (((tid & 3) ^ ((tid >> 3) & 3)) * 16);
  int lw = wv * 1024;
  floatx4 acc[4][4];
#pragma unroll
  for (int i = 0; i < 4; ++i)
#pragma unroll
    for (int j = 0; j < 4; ++j) acc[i][j] = (floatx4){0.f, 0.f, 0.f, 0.f};

  auto stage = [&](int kt, unsigned short* Ad, unsigned short* Bd) {
    size_t o = (size_t)kt * 8192;
    glds16(At + o + swzb, (char*)Ad + lw);
    glds16(At + o + 4096 + swzb, (char*)Ad + 4096 + lw);
    glds16(Bt + o + swzb, (char*)Bd + lw);
    glds16(Bt + o + 4096 + swzb, (char*)Bd + 4096 + lw);
  };
  auto compute = [&](const unsigned short* Ac, const unsigned short* Bc) {
    short8 af[4], bf[4];
#pragma unroll
    for (int mi = 0; mi < 4; ++mi)
      af[mi] = *(const short8*)(Ac + (wm * 64 + mi * 16 + row16) * 32 + qsw8);
#pragma unroll
    for (int ni = 0; ni < 4; ++ni)
      bf[ni] = *(const short8*)(Bc + (wn * 64 + ni * 16 + row16) * 32 + qsw8);
#pragma unroll
    for (int mi = 0; mi < 4; ++mi)
#pragma unroll
      for (int ni = 0; ni < 4; ++ni)
        acc[mi][ni] = __builtin_amdgcn_mfma_f32_16x16x32_bf16(af[mi], bf[ni], acc[mi][ni], 0, 0, 0);
  };

  int k0 = kz * 64;
  stage(k0 + 0, Ad0, Bd0);
  stage(k0 + 1, Ad1, Bd1);
  asm volatile("s_waitcnt vmcnt(4)" ::: "memory");   // stage(0) landed
  __builtin_amdgcn_s_barrier();
  // 64 K-steps: iters 0..61 stage t+2; loop covers 0..59, manual 60..63.
  for (int t = 0; t < 60; t += 3) {
    stage(k0 + t + 2, Ad2, Bd2);
    compute(Ad0, Bd0);
    asm volatile("s_waitcnt vmcnt(4)" ::: "memory");
    __builtin_amdgcn_s_barrier();
    stage(k0 + t + 3, Ad0, Bd0);
    compute(Ad1, Bd1);
    asm volatile("s_waitcnt vmcnt(4)" ::: "memory");
    __builtin_amdgcn_s_barrier();
    stage(k0 + t + 4, Ad1, Bd1);
    compute(Ad2, Bd2);
    asm volatile("s_waitcnt vmcnt(4)" ::: "memory");
    __builtin_amdgcn_s_barrier();
  }
  stage(k0 + 62, Ad2, Bd2);            // t=60
  compute(Ad0, Bd0);
  asm volatile("s_waitcnt vmcnt(4)" ::: "memory");
  __builtin_amdgcn_s_barrier();
  stage(k0 + 63, Ad0, Bd0);            // t=61
  compute(Ad1, Bd1);
  asm volatile("s_waitcnt vmcnt(4)" ::: "memory");
  __builtin_amdgcn_s_barrier();
  compute(Ad2, Bd2);                   // t=62
  asm volatile("s_waitcnt vmcnt(0)" ::: "memory");
  __builtin_amdgcn_s_barrier();
  compute(Ad0, Bd0);                   // t=63

#pragma unroll
  for (int mi = 0; mi < 4; ++mi)
#pragma unroll
    for (int ni = 0; ni < 4; ++ni)
#pragma unroll
      for (int r = 0; r < 4; ++r) {
        int grow = mt * 128 + wm * 64 + mi * 16 + quad * 4 + r;
        int col = ntile * 128 + wn * 64 + ni * 16 + row16;
        float scale = (grow < SHB) ? row_scale[grow] : 0.0625f;
        O[(size_t)grow * D + col] = acc[mi][ni][r] * scale;
      }
}

// ---------------- combine: out = sum over {r0, r1, shared} x {2 k-halves} ----------------
__global__ void combine_kernel(const float* __restrict__ O, const int* __restrict__ tok_rows,
                               float* __restrict__ out) {
  int idx = blockIdx.x * 256 + threadIdx.x;  // T * D/4
  int t = idx >> 8, c = idx & 255;
  int r0 = tok_rows[2 * t], r1 = tok_rows[2 * t + 1];
  const float4* O4 = (const float4*)O;
  const size_t HLF = (size_t)NROWS * 256;
  float4 a = O4[(size_t)r0 * 256 + c];
  float4 b = O4[(size_t)r1 * 256 + c];
  float4 s = O4[((size_t)SHB + t) * 256 + c];
  float4 a2 = O4[HLF + (size_t)r0 * 256 + c];
  float4 b2 = O4[HLF + (size_t)r1 * 256 + c];
  float4 s2 = O4[HLF + ((size_t)SHB + t) * 256 + c];
  float4 r;
  r.x = a.x + b.x + s.x + a2.x + b2.x + s2.x;
  r.y = a.y + b.y + s.y + a2.y + b2.y + s2.y;
  r.z = a.z + b.z + s.z + a2.z + b2.z + s2.z;
  r.w = a.w + b.w + s.w + a2.w + b2.w + s2.w;
  ((float4*)out)[idx] = r;
}

extern "C" void kernel_launch(void* const* d_in, const int* in_sizes, int n_in,
                              void* d_out, int out_size, void* d_ws, size_t ws_size,
                              hipStream_t stream) {
  (void)in_sizes; (void)n_in; (void)out_size; (void)ws_size;
  const float* x   = (const float*)d_in[0];
  const float* gW  = (const float*)d_in[1];
  const float* w1e = (const float*)d_in[2];
  const float* w3e = (const float*)d_in[3];
  const float* w2e = (const float*)d_in[4];
  const float* w1s = (const float*)d_in[5];
  const float* w3s = (const float*)d_in[6];
  const float* w2s = (const float*)d_in[7];
  float* out = (float*)d_out;

  char* w = (char*)d_ws;
  auto alloc = [&](size_t bytes) {
    char* p = w; w += (bytes + 255) & ~(size_t)255; return p;
  };
  unsigned short* xb   = (unsigned short*)alloc((size_t)T * D * 2);
  unsigned short* W1T  = (unsigned short*)alloc((size_t)E * F * D * 2);
  unsigned short* W3T  = (unsigned short*)alloc((size_t)E * F * D * 2);
  unsigned short* W2T  = (unsigned short*)alloc((size_t)E * D * F * 2);
  unsigned short* W1sT = (unsigned short*)alloc((size_t)F * D * 2);
  unsigned short* W3sT = (unsigned short*)alloc((size_t)F * D * 2);
  unsigned short* W2sT = (unsigned short*)alloc((size_t)D * F * 2);
  unsigned short* Hb   = (unsigned short*)alloc((size_t)NROWS * F * 2);
  float* Ob        = (float*)alloc((size_t)2 * NROWS * D * 4);
  float* row_scale = (float*)alloc((size_t)SHB * 4);
  float* list_gate = (float*)alloc((size_t)E * T * 4);
  int* list_tok    = (int*)alloc((size_t)E * T * 4);
  int* tok_rows    = (int*)alloc((size_t)T * 2 * 4);
  int* offv        = (int*)alloc(16 * 4);
  int* mt_expert   = (int*)alloc(64 * 4);
  int* ctrl        = (int*)alloc((size_t)(8 + T + SHB) * 4);
  int* cnt = ctrl; int* tk = ctrl + 8; int* tok_of_row = ctrl + 8 + T;

  hipMemsetAsync(ctrl, 0, (size_t)(8 + T + SHB) * 4, stream);
  gate_kernel<<<T, 256, 0, stream>>>(x, gW, xb, cnt, list_tok, list_gate);
  offsets_kernel<<<1, 64, 0, stream>>>(cnt, offv, mt_expert);
  scatter_kernel<<<(E * T) / 256, 256, 0, stream>>>(cnt, offv, list_tok, list_gate,
                                                    tok_of_row, row_scale, tok_rows, tk);
  transpose_cast<<<dim3(F / 32, D / 32, E), 256, 0, stream>>>(w1e, W1T, D, F);
  transpose_cast<<<dim3(F / 32, D / 32, E), 256, 0, stream>>>(w3e, W3T, D, F);
  transpose_cast<<<dim3(D / 32, F / 32, E), 256, 0, stream>>>(w2e, W2T, F, D);
  transpose_cast<<<dim3(FS / 32, D / 32, NS), 256, 0, stream>>>(w1s, W1sT, D, FS);
  transpose_cast<<<dim3(FS / 32, D / 32, NS), 256, 0, stream>>>(w3s, W3sT, D, FS);
  transpose_cast<<<dim3(D / 32, F / 32, 1), 256, 0, stream>>>(w2s, W2sT, F, D);
  up_gemm<<<dim3(F / 128, MT_MAX), 256, 0, stream>>>(xb, W1T, W3T, W1sT, W3sT,
                                                     mt_expert, tok_of_row, Hb);
  down_gemm<<<dim3(D / 128, MT_MAX, 2), 256, 0, stream>>>(Hb, W2T, W2sT, mt_expert, row_scale, Ob);
  combine_kernel<<<(T * D / 4) / 256, 256, 0, stream>>>(Ob, tok_rows, out);
}

// Round 4
// 698.330 us; speedup vs baseline: 1.1005x; 1.0337x over previous
//
#include <hip/hip_runtime.h>

#define T 2048
#define D 1024
#define F 4096
#define E 8
#define NS 8
#define FS 512
#define SHB 5120      // shared-expert H base row (routed padded capacity)
#define NROWS 7168    // SHB + T
#define MT_MAX 56     // NROWS/128

typedef float floatx4 __attribute__((ext_vector_type(4)));
typedef short short8 __attribute__((ext_vector_type(8)));
typedef unsigned short ushort8v __attribute__((ext_vector_type(8)));

__device__ __forceinline__ unsigned short f2bf(float f) {
  unsigned int u = __float_as_uint(f);
  u += 0x7FFF + ((u >> 16) & 1);   // RNE
  return (unsigned short)(u >> 16);
}

__device__ __forceinline__ void glds16(const void* g, void* l) {
  __builtin_amdgcn_global_load_lds(
      (const __attribute__((address_space(1))) void*)g,
      (__attribute__((address_space(3))) void*)l, 16, 0, 0);
}

// ---------------- gate: logits, softmax, top-2, x -> bf16 (vectorized) ----------------
__global__ void gate_kernel(const float* __restrict__ x, const float* __restrict__ gW,
                            unsigned short* __restrict__ xb, int* __restrict__ cnt,
                            int* __restrict__ list_tok, float* __restrict__ list_gate) {
  int t = blockIdx.x, tid = threadIdx.x;
  const float4* xr = (const float4*)(x + (size_t)t * D);
  const float4* g4 = (const float4*)gW;
  float4 xv = xr[tid];                       // D/4 = 256 = blockDim
  ushort4 xo;
  xo.x = f2bf(xv.x); xo.y = f2bf(xv.y); xo.z = f2bf(xv.z); xo.w = f2bf(xv.w);
  *(ushort4*)(xb + (size_t)t * D + tid * 4) = xo;
  float acc[E];
#pragma unroll
  for (int e = 0; e < E; ++e) {
    float4 w = g4[e * 256 + tid];
    acc[e] = xv.x * w.x + xv.y * w.y + xv.z * w.z + xv.w * w.w;
  }
#pragma unroll
  for (int o = 32; o > 0; o >>= 1)
#pragma unroll
    for (int e = 0; e < E; ++e) acc[e] += __shfl_down(acc[e], o, 64);
  __shared__ float wred[4][E];
  int lane = tid & 63, wv = tid >> 6;
  if (lane == 0)
#pragma unroll
    for (int e = 0; e < E; ++e) wred[wv][e] = acc[e];
  __syncthreads();
  if (tid == 0) {
    float l[E];
#pragma unroll
    for (int e = 0; e < E; ++e) l[e] = wred[0][e] + wred[1][e] + wred[2][e] + wred[3][e];
    int i1 = 0; float m1 = l[0];
    for (int e = 1; e < E; ++e) if (l[e] > m1) { m1 = l[e]; i1 = e; }
    int i2 = -1; float m2 = -3.4e38f;
    for (int e = 0; e < E; ++e) if (e != i1 && l[e] > m2) { m2 = l[e]; i2 = e; }
    float s = 0.f, p[E];
#pragma unroll
    for (int e = 0; e < E; ++e) { p[e] = __expf(l[e] - m1); s += p[e]; }
    float inv = 1.f / s;
    int p1 = atomicAdd(&cnt[i1], 1);
    list_tok[i1 * T + p1] = t; list_gate[i1 * T + p1] = p[i1] * inv;
    int p2 = atomicAdd(&cnt[i2], 1);
    list_tok[i2 * T + p2] = t; list_gate[i2 * T + p2] = p[i2] * inv;
  }
}

// ---------------- offsets (1 thread): 128-aligned segment starts ----------------
__global__ void offsets_kernel(const int* __restrict__ cnt, int* __restrict__ off,
                               int* __restrict__ mt_expert) {
  if (threadIdx.x == 0 && blockIdx.x == 0) {
    int o = 0;
    for (int e = 0; e < E; ++e) { off[e] = o; o += (cnt[e] + 127) & ~127; }
    off[E] = o;
    for (int i = 0; i < MT_MAX; ++i) mt_expert[i] = -1;
    for (int e = 0; e < E; ++e) {
      int t0 = off[e] >> 7, nt = (cnt[e] + 127) >> 7;
      for (int i = 0; i < nt; ++i) mt_expert[t0 + i] = e;
    }
    for (int i = SHB >> 7; i < MT_MAX; ++i) mt_expert[i] = E;
  }
}

// ---------------- scatter: row maps + per-row scales ----------------
__global__ void scatter_kernel(const int* __restrict__ cnt, const int* __restrict__ off,
                               const int* __restrict__ list_tok, const float* __restrict__ list_gate,
                               int* __restrict__ tok_of_row, float* __restrict__ row_scale,
                               int* __restrict__ tok_rows, int* __restrict__ tk) {
  int idx = blockIdx.x * 256 + threadIdx.x;  // E*T
  int e = idx >> 11, i = idx & (T - 1);
  if (e < E && i < cnt[e]) {
    int row = off[e] + i;
    int t = list_tok[e * T + i];
    tok_of_row[row] = t;
    row_scale[row] = 0.5f * list_gate[e * T + i];
    int k = atomicAdd(&tk[t], 1);
    tok_rows[2 * t + k] = row;
  }
}

// ------- transpose+cast fp32 [R,C] -> bf16 B^T tiled [C/128][R/32][128][32] -------
// 64r x 64c tile, 256 threads: float4-coalesced reads, ushort8 (16B) coalesced stores.
__device__ __forceinline__ void tc64(const float* __restrict__ in,
                                     unsigned short* __restrict__ out, int R, int C) {
  int r0 = blockIdx.y * 64, c0 = blockIdx.x * 64;
  __shared__ float tile[64][65];
  int tid = threadIdx.x;
  {
    int cl4 = (tid & 15) * 4;       // col offset, float4
    int rl0 = tid >> 4;             // 0..15
#pragma unroll
    for (int k = 0; k < 4; ++k) {
      int rl = rl0 + k * 16;
      float4 v = *(const float4*)(in + (size_t)(r0 + rl) * C + c0 + cl4);
      tile[rl][cl4] = v.x; tile[rl][cl4 + 1] = v.y;
      tile[rl][cl4 + 2] = v.z; tile[rl][cl4 + 3] = v.w;
    }
  }
  __syncthreads();
  {
    int cl = tid >> 2;              // 0..63
    int rq = tid & 3;               // 8-row group within a 32-row half
    int c = c0 + cl;
    int Rt = R >> 5;
    size_t cbase = ((size_t)(c >> 7) * Rt) * 4096 + (size_t)(c & 127) * 32;
#pragma unroll
    for (int s = 0; s < 2; ++s) {
      int rr = s * 32 + rq * 8;     // row offset within 64-tile
      int r = r0 + rr;              // r&31 == rq*8 (r0 is 64-aligned)
      ushort8v v;
#pragma unroll
      for (int j = 0; j < 8; ++j) v[j] = f2bf(tile[rr + j][cl]);
      size_t o = cbase + (size_t)(r >> 5) * 4096 + (r & 31);
      *(ushort8v*)(out + o) = v;    // 16B aligned store
    }
  }
}

__global__ void transpose_cast(const float* __restrict__ in, unsigned short* __restrict__ out,
                               int R, int C) {
  tc64(in + (size_t)blockIdx.z * R * C, out + (size_t)blockIdx.z * R * C, R, C);
}

__global__ void transpose_cast_pair(const float* __restrict__ inA, const float* __restrict__ inB,
                                    unsigned short* __restrict__ outA,
                                    unsigned short* __restrict__ outB, int R, int C) {
  int z = blockIdx.z, h = gridDim.z >> 1;
  const float* in = (z < h) ? inA : inB;
  unsigned short* out = (z < h) ? outA : outB;
  int zz = (z < h) ? z : z - h;
  tc64(in + (size_t)zz * R * C, out + (size_t)zz * R * C, R, C);
}

// ---------------- up GEMM: H = silu(A@W1) * (A@W3), grouped by expert ----------------
// Depth-2 pipeline (T4 counted-vmcnt): 3 static LDS buffers, raw s_barrier, manual
// s_waitcnt vmcnt(6) (= one stage's glds count) so a full stage stays in flight
// across each barrier. Iteration: [stage(t+2); compute(t); vmcnt(6); s_barrier].
// LDS XOR-swizzle: 16B slot j of row r holds global slot j ^ ((r>>1)&3).
__global__ __launch_bounds__(256, 2) void up_gemm(
    const unsigned short* __restrict__ xb, const unsigned short* __restrict__ W1T,
    const unsigned short* __restrict__ W3T, const unsigned short* __restrict__ W1sT,
    const unsigned short* __restrict__ W3sT, const int* __restrict__ mt_expert,
    const int* __restrict__ tok_of_row, unsigned short* __restrict__ Hb) {
  int mt = blockIdx.y, ntile = blockIdx.x;
  int e = mt_expert[mt];
  if (e < 0) return;
  const unsigned short *B1, *B3;
  if (e < E) {
    B1 = W1T + (size_t)e * F * D;
    B3 = W3T + (size_t)e * F * D;
  } else {
    B1 = W1sT; B3 = W3sT;
  }
  __shared__ unsigned short Au0[128 * 32], B1u0[128 * 32], B3u0[128 * 32];
  __shared__ unsigned short Au1[128 * 32], B1u1[128 * 32], B3u1[128 * 32];
  __shared__ unsigned short Au2[128 * 32], B1u2[128 * 32], B3u2[128 * 32];
  int tid = threadIdx.x;
  int lane = tid & 63, wv = tid >> 6, wm = wv >> 1, wn = wv & 1;
  int row16 = lane & 15, quad = lane >> 4;
  int qsw8 = (quad ^ ((lane >> 1) & 3)) * 8;   // swizzled read slot, in shorts
  int swzb = (tid >> 2) * 64 + (((tid & 3) ^ ((tid >> 3) & 3)) * 16);  // staging src byte off
  int lw = wv * 1024;  // wave LDS byte offset (glds dest must be wave-uniform)

  int r1 = tid >> 2;
  int hrow1 = mt * 128 + r1, hrow2 = hrow1 + 64;
  int srow1 = (e < E) ? tok_of_row[hrow1] : (hrow1 - SHB);
  int srow2 = (e < E) ? tok_of_row[hrow2] : (hrow2 - SHB);
  int asl = ((tid & 3) ^ ((tid >> 3) & 3)) * 16;
  const char* asrc1 = (const char*)(xb + (size_t)srow1 * D) + asl;
  const char* asrc2 = (const char*)(xb + (size_t)srow2 * D) + asl;
  const char* b1t = (const char*)(B1 + (size_t)ntile * (D / 32) * 4096);
  const char* b3t = (const char*)(B3 + (size_t)ntile * (D / 32) * 4096);

  floatx4 accg[4][4], accu[4][4];
#pragma unroll
  for (int i = 0; i < 4; ++i)
#pragma unroll
    for (int j = 0; j < 4; ++j) {
      accg[i][j] = (floatx4){0.f, 0.f, 0.f, 0.f};
      accu[i][j] = (floatx4){0.f, 0.f, 0.f, 0.f};
    }

  auto stage = [&](int kt, unsigned short* Ad, unsigned short* B1d, unsigned short* B3d) {
    size_t ko = (size_t)kt * 64;     // A advances 32 bf16 = 64 B per K-step
    size_t bo = (size_t)kt * 8192;   // B tile = 8 KB per K-step
    glds16(asrc1 + ko, (char*)Ad + lw);
    glds16(asrc2 + ko, (char*)Ad + 4096 + lw);
    glds16(b1t + bo + swzb, (char*)B1d + lw);
    glds16(b1t + bo + 4096 + swzb, (char*)B1d + 4096 + lw);
    glds16(b3t + bo + swzb, (char*)B3d + lw);
    glds16(b3t + bo + 4096 + swzb, (char*)B3d + 4096 + lw);
  };
  auto compute = [&](const unsigned short* Ac, const unsigned short* B1c,
                     const unsigned short* B3c) {
    short8 af[4], b1f[4], b3f[4];
#pragma unroll
    for (int mi = 0; mi < 4; ++mi)
      af[mi] = *(const short8*)(Ac + (wm * 64 + mi * 16 + row16) * 32 + qsw8);
#pragma unroll
    for (int ni = 0; ni < 4; ++ni) {
      b1f[ni] = *(const short8*)(B1c + (wn * 64 + ni * 16 + row16) * 32 + qsw8);
      b3f[ni] = *(const short8*)(B3c + (wn * 64 + ni * 16 + row16) * 32 + qsw8);
    }
#pragma unroll
    for (int mi = 0; mi < 4; ++mi)
#pragma unroll
      for (int ni = 0; ni < 4; ++ni) {
        accg[mi][ni] = __builtin_amdgcn_mfma_f32_16x16x32_bf16(af[mi], b1f[ni], accg[mi][ni], 0, 0, 0);
        accu[mi][ni] = __builtin_amdgcn_mfma_f32_16x16x32_bf16(af[mi], b3f[ni], accu[mi][ni], 0, 0, 0);
      }
  };

  stage(0, Au0, B1u0, B3u0);
  stage(1, Au1, B1u1, B3u1);
  asm volatile("s_waitcnt vmcnt(6)" ::: "memory");   // stage(0) landed
  __builtin_amdgcn_s_barrier();
  for (int t = 0; t < 30; t += 3) {
    stage(t + 2, Au2, B1u2, B3u2);
    compute(Au0, B1u0, B3u0);
    asm volatile("s_waitcnt vmcnt(6)" ::: "memory");
    __builtin_amdgcn_s_barrier();
    stage(t + 3, Au0, B1u0, B3u0);
    compute(Au1, B1u1, B3u1);
    asm volatile("s_waitcnt vmcnt(6)" ::: "memory");
    __builtin_amdgcn_s_barrier();
    stage(t + 4, Au1, B1u1, B3u1);
    compute(Au2, B1u2, B3u2);
    asm volatile("s_waitcnt vmcnt(6)" ::: "memory");
    __builtin_amdgcn_s_barrier();
  }
  compute(Au0, B1u0, B3u0);            // t=30
  asm volatile("s_waitcnt vmcnt(0)" ::: "memory");   // stage(31) landed
  __builtin_amdgcn_s_barrier();
  compute(Au1, B1u1, B3u1);            // t=31

  // epilogue: silu(g)*u -> bf16, H in tiled layout
#pragma unroll
  for (int mi = 0; mi < 4; ++mi)
#pragma unroll
    for (int ni = 0; ni < 4; ++ni)
#pragma unroll
      for (int r = 0; r < 4; ++r) {
        int hrow = mt * 128 + wm * 64 + mi * 16 + quad * 4 + r;
        int col = ntile * 128 + wn * 64 + ni * 16 + row16;
        float g = accg[mi][ni][r], u = accu[mi][ni][r];
        float h = g * u / (1.0f + __expf(-g));
        size_t o = ((size_t)(hrow >> 7) * 128 + (col >> 5)) * 4096 + (size_t)(hrow & 127) * 32 + (col & 31);
        Hb[o] = f2bf(h);
      }
}

// ---------------- down GEMM: O = (H @ W2) * row_scale, full-K ----------------
// Same depth-2 counted-vmcnt pipeline; stage width = 4 glds -> vmcnt(4). 128 K-steps.
__global__ __launch_bounds__(256, 2) void down_gemm(
    const unsigned short* __restrict__ Hb, const unsigned short* __restrict__ W2T,
    const unsigned short* __restrict__ W2sT, const int* __restrict__ mt_expert,
    const float* __restrict__ row_scale, float* __restrict__ O) {
  int mt = blockIdx.y, ntile = blockIdx.x;
  int e = mt_expert[mt];
  if (e < 0) return;
  const char* Bt = (const char*)(((e < E) ? (W2T + (size_t)e * D * F) : W2sT)
                                 + (size_t)ntile * (F / 32) * 4096);
  const char* At = (const char*)(Hb + (size_t)mt * (F / 32) * 4096);
  __shared__ unsigned short Ad0[128 * 32], Bd0[128 * 32];
  __shared__ unsigned short Ad1[128 * 32], Bd1[128 * 32];
  __shared__ unsigned short Ad2[128 * 32], Bd2[128 * 32];
  int tid = threadIdx.x;
  int lane = tid & 63, wv = tid >> 6, wm = wv >> 1, wn = wv & 1;
  int row16 = lane & 15, quad = lane >> 4;
  int qsw8 = (quad ^ ((lane >> 1) & 3)) * 8;
  int swzb = (tid >> 2) * 64 + (((tid & 3) ^ ((tid >> 3) & 3)) * 16);
  int lw = wv * 1024;
  floatx4 acc[4][4];
#pragma unroll
  for (int i = 0; i < 4; ++i)
#pragma unroll
    for (int j = 0; j < 4; ++j) acc[i][j] = (floatx4){0.f, 0.f, 0.f, 0.f};

  auto stage = [&](int kt, unsigned short* Ad, unsigned short* Bd) {
    size_t o = (size_t)kt * 8192;
    glds16(At + o + swzb, (char*)Ad + lw);
    glds16(At + o + 4096 + swzb, (char*)Ad + 4096 + lw);
    glds16(Bt + o + swzb, (char*)Bd + lw);
    glds16(Bt + o + 4096 + swzb, (char*)Bd + 4096 + lw);
  };
  auto compute = [&](const unsigned short* Ac, const unsigned short* Bc) {
    short8 af[4], bf[4];
#pragma unroll
    for (int mi = 0; mi < 4; ++mi)
      af[mi] = *(const short8*)(Ac + (wm * 64 + mi * 16 + row16) * 32 + qsw8);
#pragma unroll
    for (int ni = 0; ni < 4; ++ni)
      bf[ni] = *(const short8*)(Bc + (wn * 64 + ni * 16 + row16) * 32 + qsw8);
#pragma unroll
    for (int mi = 0; mi < 4; ++mi)
#pragma unroll
      for (int ni = 0; ni < 4; ++ni)
        acc[mi][ni] = __builtin_amdgcn_mfma_f32_16x16x32_bf16(af[mi], bf[ni], acc[mi][ni], 0, 0, 0);
  };

  stage(0, Ad0, Bd0);
  stage(1, Ad1, Bd1);
  asm volatile("s_waitcnt vmcnt(4)" ::: "memory");   // stage(0) landed
  __builtin_amdgcn_s_barrier();
  // 128 K-steps: loop computes 0..125 (42 x 3), staging through 127; 2 drain steps.
  for (int t = 0; t < 126; t += 3) {
    stage(t + 2, Ad2, Bd2);
    compute(Ad0, Bd0);
    asm volatile("s_waitcnt vmcnt(4)" ::: "memory");
    __builtin_amdgcn_s_barrier();
    stage(t + 3, Ad0, Bd0);
    compute(Ad1, Bd1);
    asm volatile("s_waitcnt vmcnt(4)" ::: "memory");
    __builtin_amdgcn_s_barrier();
    stage(t + 4, Ad1, Bd1);
    compute(Ad2, Bd2);
    asm volatile("s_waitcnt vmcnt(4)" ::: "memory");
    __builtin_amdgcn_s_barrier();
  }
  compute(Ad0, Bd0);                   // t=126
  asm volatile("s_waitcnt vmcnt(0)" ::: "memory");   // stage(127) landed
  __builtin_amdgcn_s_barrier();
  compute(Ad1, Bd1);                   // t=127

#pragma unroll
  for (int mi = 0; mi < 4; ++mi)
#pragma unroll
    for (int ni = 0; ni < 4; ++ni)
#pragma unroll
      for (int r = 0; r < 4; ++r) {
        int grow = mt * 128 + wm * 64 + mi * 16 + quad * 4 + r;
        int col = ntile * 128 + wn * 64 + ni * 16 + row16;
        float scale = (grow < SHB) ? row_scale[grow] : 0.0625f;
        O[(size_t)grow * D + col] = acc[mi][ni][r] * scale;
      }
}

// ---------------- combine: out = r0 + r1 + shared ----------------
__global__ void combine_kernel(const float* __restrict__ O, const int* __restrict__ tok_rows,
                               float* __restrict__ out) {
  int idx = blockIdx.x * 256 + threadIdx.x;  // T * D/4
  int t = idx >> 8, c = idx & 255;
  int r0 = tok_rows[2 * t], r1 = tok_rows[2 * t + 1];
  const float4* O4 = (const float4*)O;
  float4 a = O4[(size_t)r0 * 256 + c];
  float4 b = O4[(size_t)r1 * 256 + c];
  float4 s = O4[((size_t)SHB + t) * 256 + c];
  float4 r;
  r.x = a.x + b.x + s.x;
  r.y = a.y + b.y + s.y;
  r.z = a.z + b.z + s.z;
  r.w = a.w + b.w + s.w;
  ((float4*)out)[idx] = r;
}

extern "C" void kernel_launch(void* const* d_in, const int* in_sizes, int n_in,
                              void* d_out, int out_size, void* d_ws, size_t ws_size,
                              hipStream_t stream) {
  (void)in_sizes; (void)n_in; (void)out_size; (void)ws_size;
  const float* x   = (const float*)d_in[0];
  const float* gW  = (const float*)d_in[1];
  const float* w1e = (const float*)d_in[2];
  const float* w3e = (const float*)d_in[3];
  const float* w2e = (const float*)d_in[4];
  const float* w1s = (const float*)d_in[5];
  const float* w3s = (const float*)d_in[6];
  const float* w2s = (const float*)d_in[7];
  float* out = (float*)d_out;

  char* w = (char*)d_ws;
  auto alloc = [&](size_t bytes) {
    char* p = w; w += (bytes + 255) & ~(size_t)255; return p;
  };
  unsigned short* xb   = (unsigned short*)alloc((size_t)T * D * 2);
  unsigned short* W1T  = (unsigned short*)alloc((size_t)E * F * D * 2);
  unsigned short* W3T  = (unsigned short*)alloc((size_t)E * F * D * 2);
  unsigned short* W2T  = (unsigned short*)alloc((size_t)E * D * F * 2);
  unsigned short* W1sT = (unsigned short*)alloc((size_t)F * D * 2);
  unsigned short* W3sT = (unsigned short*)alloc((size_t)F * D * 2);
  unsigned short* W2sT = (unsigned short*)alloc((size_t)D * F * 2);
  unsigned short* Hb   = (unsigned short*)alloc((size_t)NROWS * F * 2);
  float* Ob        = (float*)alloc((size_t)NROWS * D * 4);
  float* row_scale = (float*)alloc((size_t)SHB * 4);
  float* list_gate = (float*)alloc((size_t)E * T * 4);
  int* list_tok    = (int*)alloc((size_t)E * T * 4);
  int* tok_rows    = (int*)alloc((size_t)T * 2 * 4);
  int* offv        = (int*)alloc(16 * 4);
  int* mt_expert   = (int*)alloc(64 * 4);
  int* ctrl        = (int*)alloc((size_t)(8 + T + SHB) * 4);
  int* cnt = ctrl; int* tk = ctrl + 8; int* tok_of_row = ctrl + 8 + T;

  hipMemsetAsync(ctrl, 0, (size_t)(8 + T + SHB) * 4, stream);
  gate_kernel<<<T, 256, 0, stream>>>(x, gW, xb, cnt, list_tok, list_gate);
  offsets_kernel<<<1, 64, 0, stream>>>(cnt, offv, mt_expert);
  scatter_kernel<<<(E * T) / 256, 256, 0, stream>>>(cnt, offv, list_tok, list_gate,
                                                    tok_of_row, row_scale, tok_rows, tk);
  transpose_cast_pair<<<dim3(F / 64, D / 64, 2 * E), 256, 0, stream>>>(w1e, w3e, W1T, W3T, D, F);
  transpose_cast<<<dim3(D / 64, F / 64, E), 256, 0, stream>>>(w2e, W2T, F, D);
  transpose_cast_pair<<<dim3(FS / 64, D / 64, 2 * NS), 256, 0, stream>>>(w1s, w3s, W1sT, W3sT, D, FS);
  transpose_cast<<<dim3(D / 64, F / 64, 1), 256, 0, stream>>>(w2s, W2sT, F, D);
  up_gemm<<<dim3(F / 128, MT_MAX), 256, 0, stream>>>(xb, W1T, W3T, W1sT, W3sT,
                                                     mt_expert, tok_of_row, Hb);
  down_gemm<<<dim3(D / 128, MT_MAX), 256, 0, stream>>>(Hb, W2T, W2sT, mt_expert, row_scale, Ob);
  combine_kernel<<<(T * D / 4) / 256, 256, 0, stream>>>(Ob, tok_rows, out);
}

// Round 5
// 666.308 us; speedup vs baseline: 1.1533x; 1.0481x over previous
//
#include <hip/hip_runtime.h>

#define T 2048
#define D 1024
#define F 4096
#define E 8
#define NS 8
#define FS 512
#define SHB 5120      // shared-expert H base row (routed padded capacity)
#define NROWS 7168    // SHB + T
#define MT_MAX 56     // NROWS/128

typedef float floatx4 __attribute__((ext_vector_type(4)));
typedef short short8 __attribute__((ext_vector_type(8)));
typedef unsigned short ushort8v __attribute__((ext_vector_type(8)));

__device__ __forceinline__ unsigned short f2bf(float f) {
  unsigned int u = __float_as_uint(f);
  u += 0x7FFF + ((u >> 16) & 1);   // RNE
  return (unsigned short)(u >> 16);
}

__device__ __forceinline__ void glds16(const void* g, void* l) {
  __builtin_amdgcn_global_load_lds(
      (const __attribute__((address_space(1))) void*)g,
      (__attribute__((address_space(3))) void*)l, 16, 0, 0);
}

// route: find expert segment for a 128-row tile at row r0b; returns e (E = shared,
// -1 = dead padding zone), segment base row (obase) and real count (ccnt).
// No local arrays -> stays in registers/SGPRs.
__device__ __forceinline__ int route(const int* __restrict__ cnt, int r0b,
                                     int& obase, int& ccnt) {
  int e = -1, o = 0, ob = 0, cc = 0;
#pragma unroll
  for (int i = 0; i < E; ++i) {
    int c = cnt[i];
    int p = (c + 127) & ~127;
    if (r0b >= o && r0b < o + p) { e = i; ob = o; cc = c; }
    o += p;
  }
  if (r0b >= SHB) e = E;
  obase = ob; ccnt = cc;
  return e;
}

// off[e] without a dynamically-indexed array (branch-free).
__device__ __forceinline__ int seg_off(const int* __restrict__ cnt, int e) {
  int o = 0;
#pragma unroll
  for (int i = 0; i < E; ++i) { int p = (cnt[i] + 127) & ~127; o += (i < e) ? p : 0; }
  return o;
}

// ------- transpose+cast fp32 [R,C] -> bf16 B^T tiled [C/128][R/32][128][32] -------
// 64r x 64c tile, 256 threads: float4-coalesced reads, ushort8 (16B) coalesced stores.
__device__ __forceinline__ void tc64(const float* __restrict__ in,
                                     unsigned short* __restrict__ out, int R, int C,
                                     int bx, int by, float tile[64][65]) {
  int r0 = by * 64, c0 = bx * 64;
  int tid = threadIdx.x;
  {
    int cl4 = (tid & 15) * 4;
    int rl0 = tid >> 4;
#pragma unroll
    for (int k = 0; k < 4; ++k) {
      int rl = rl0 + k * 16;
      float4 v = *(const float4*)(in + (size_t)(r0 + rl) * C + c0 + cl4);
      tile[rl][cl4] = v.x; tile[rl][cl4 + 1] = v.y;
      tile[rl][cl4 + 2] = v.z; tile[rl][cl4 + 3] = v.w;
    }
  }
  __syncthreads();
  {
    int cl = tid >> 2, rq = tid & 3;
    int c = c0 + cl;
    int Rt = R >> 5;
    size_t cbase = ((size_t)(c >> 7) * Rt) * 4096 + (size_t)(c & 127) * 32;
#pragma unroll
    for (int s = 0; s < 2; ++s) {
      int rr = s * 32 + rq * 8;
      int r = r0 + rr;
      ushort8v v;
#pragma unroll
      for (int j = 0; j < 8; ++j) v[j] = f2bf(tile[rr + j][cl]);
      size_t o = cbase + (size_t)(r >> 5) * 4096 + (r & 31);
      *(ushort8v*)(out + o) = v;
    }
  }
}

// ---------------- gate body: logits, softmax, top-2, x -> bf16 ----------------
__device__ __forceinline__ void gate_body(const float* __restrict__ x,
                                          const float* __restrict__ gW,
                                          unsigned short* __restrict__ xb,
                                          int* __restrict__ cnt,
                                          int* __restrict__ list_tok,
                                          float* __restrict__ list_gate,
                                          int* __restrict__ assign, int t, float* wred) {
  int tid = threadIdx.x;
  const float4* xr = (const float4*)(x + (size_t)t * D);
  const float4* g4 = (const float4*)gW;
  float4 xv = xr[tid];                       // D/4 = 256 = blockDim
  ushort4 xo;
  xo.x = f2bf(xv.x); xo.y = f2bf(xv.y); xo.z = f2bf(xv.z); xo.w = f2bf(xv.w);
  *(ushort4*)(xb + (size_t)t * D + tid * 4) = xo;
  float acc[E];
#pragma unroll
  for (int e = 0; e < E; ++e) {
    float4 w = g4[e * 256 + tid];
    acc[e] = xv.x * w.x + xv.y * w.y + xv.z * w.z + xv.w * w.w;
  }
#pragma unroll
  for (int o = 32; o > 0; o >>= 1)
#pragma unroll
    for (int e = 0; e < E; ++e) acc[e] += __shfl_down(acc[e], o, 64);
  int lane = tid & 63, wv = tid >> 6;
  if (lane == 0)
#pragma unroll
    for (int e = 0; e < E; ++e) wred[wv * E + e] = acc[e];
  __syncthreads();
  if (tid == 0) {
    float l[E];
#pragma unroll
    for (int e = 0; e < E; ++e) l[e] = wred[0 * E + e] + wred[1 * E + e] + wred[2 * E + e] + wred[3 * E + e];
    int i1 = 0; float m1 = l[0];
    for (int e = 1; e < E; ++e) if (l[e] > m1) { m1 = l[e]; i1 = e; }
    int i2 = -1; float m2 = -3.4e38f;
    for (int e = 0; e < E; ++e) if (e != i1 && l[e] > m2) { m2 = l[e]; i2 = e; }
    float s = 0.f, p[E];
#pragma unroll
    for (int e = 0; e < E; ++e) { p[e] = __expf(l[e] - m1); s += p[e]; }
    float inv = 1.f / s;
    int p1 = atomicAdd(&cnt[i1], 1);
    list_tok[i1 * T + p1] = t; list_gate[i1 * T + p1] = p[i1] * inv;
    assign[2 * t] = (i1 << 16) | p1;
    int p2 = atomicAdd(&cnt[i2], 1);
    list_tok[i2 * T + p2] = t; list_gate[i2 * T + p2] = p[i2] * inv;
    assign[2 * t + 1] = (i2 << 16) | p2;
  }
}

// ---------------- prep: ALL weight transposes + gate in ONE launch ----------------
// Flat block-id segments (all pow-2 decode):
//   [0,8192)      w1e  (R=D,C=F;  per-z 1024 tiles: bx=rem&63, by=rem>>6)
//   [8192,16384)  w3e  (same)
//   [16384,24576) w2e  (R=F,C=D;  per-z 1024 tiles: bx=rem&15, by=rem>>4)
//   [24576,25600) w1s  (R=D,C=FS; per-z 128 tiles:  bx=rem&7,  by=rem>>3)
//   [25600,26624) w3s  (same)
//   [26624,27648) w2s  (R=F,C=D single tensor:      bx=rem&15, by=rem>>4)
//   [27648,29696) gate for token bid-27648
__global__ void prep_kernel(const float* __restrict__ x, const float* __restrict__ gW,
                            const float* __restrict__ w1e, const float* __restrict__ w3e,
                            const float* __restrict__ w2e, const float* __restrict__ w1s,
                            const float* __restrict__ w3s, const float* __restrict__ w2s,
                            unsigned short* __restrict__ W1T, unsigned short* __restrict__ W3T,
                            unsigned short* __restrict__ W2T, unsigned short* __restrict__ W1sT,
                            unsigned short* __restrict__ W3sT, unsigned short* __restrict__ W2sT,
                            unsigned short* __restrict__ xb, int* __restrict__ cnt,
                            int* __restrict__ list_tok, float* __restrict__ list_gate,
                            int* __restrict__ assign) {
  __shared__ float tile[64][65];
  int bid = blockIdx.x;
  if (bid < 24576) {
    int seg = bid >> 13;
    int t = bid & 8191;
    int z = t >> 10, rem = t & 1023;
    if (seg == 0)
      tc64(w1e + (size_t)z * D * F, W1T + (size_t)z * D * F, D, F, rem & 63, rem >> 6, tile);
    else if (seg == 1)
      tc64(w3e + (size_t)z * D * F, W3T + (size_t)z * D * F, D, F, rem & 63, rem >> 6, tile);
    else
      tc64(w2e + (size_t)z * F * D, W2T + (size_t)z * F * D, F, D, rem & 15, rem >> 4, tile);
  } else if (bid < 26624) {
    int t = bid - 24576;
    int seg = t >> 10, tt = t & 1023;
    int z = tt >> 7, rem = tt & 127;
    if (seg == 0)
      tc64(w1s + (size_t)z * D * FS, W1sT + (size_t)z * D * FS, D, FS, rem & 7, rem >> 3, tile);
    else
      tc64(w3s + (size_t)z * D * FS, W3sT + (size_t)z * D * FS, D, FS, rem & 7, rem >> 3, tile);
  } else if (bid < 27648) {
    int rem = bid - 26624;
    tc64(w2s, W2sT, F, D, rem & 15, rem >> 4, tile);
  } else {
    gate_body(x, gW, xb, cnt, list_tok, list_gate, assign, bid - 27648, (float*)tile);
  }
}

// ---------------- up GEMM: H = silu(A@W1) * (A@W3), grouped by expert ----------------
// Depth-2 pipeline (T4 counted-vmcnt): 3 static LDS buffers, raw s_barrier, manual
// s_waitcnt vmcnt(6) (= one stage's glds count) so a full stage stays in flight
// across each barrier. Iteration: [stage(t+2); compute(t); vmcnt(6); s_barrier].
// LDS XOR-swizzle: 16B slot j of row r holds global slot j ^ ((r>>1)&3).
__global__ __launch_bounds__(256, 2) void up_gemm(
    const unsigned short* __restrict__ xb, const unsigned short* __restrict__ W1T,
    const unsigned short* __restrict__ W3T, const unsigned short* __restrict__ W1sT,
    const unsigned short* __restrict__ W3sT, const int* __restrict__ cnt,
    const int* __restrict__ list_tok, unsigned short* __restrict__ Hb) {
  int mt = blockIdx.y, ntile = blockIdx.x;
  int obase, ccnt;
  int e = route(cnt, mt * 128, obase, ccnt);
  if (e < 0) return;
  const unsigned short *B1, *B3;
  if (e < E) {
    B1 = W1T + (size_t)e * F * D;
    B3 = W3T + (size_t)e * F * D;
  } else {
    B1 = W1sT; B3 = W3sT;
  }
  __shared__ unsigned short Au0[128 * 32], B1u0[128 * 32], B3u0[128 * 32];
  __shared__ unsigned short Au1[128 * 32], B1u1[128 * 32], B3u1[128 * 32];
  __shared__ unsigned short Au2[128 * 32], B1u2[128 * 32], B3u2[128 * 32];
  int tid = threadIdx.x;
  int lane = tid & 63, wv = tid >> 6, wm = wv >> 1, wn = wv & 1;
  int row16 = lane & 15, quad = lane >> 4;
  int qsw8 = (quad ^ ((lane >> 1) & 3)) * 8;   // swizzled read slot, in shorts
  int swzb = (tid >> 2) * 64 + (((tid & 3) ^ ((tid >> 3) & 3)) * 16);  // staging src byte off
  int lw = wv * 1024;  // wave LDS byte offset (glds dest must be wave-uniform)

  int r1 = tid >> 2;
  int hrow1 = mt * 128 + r1, hrow2 = hrow1 + 64;
  int srow1, srow2;
  if (e < E) {
    int i1 = hrow1 - obase; i1 = (i1 < ccnt) ? i1 : ccnt - 1;
    int i2 = hrow2 - obase; i2 = (i2 < ccnt) ? i2 : ccnt - 1;
    srow1 = list_tok[e * T + i1];
    srow2 = list_tok[e * T + i2];
  } else {
    srow1 = hrow1 - SHB; srow2 = hrow2 - SHB;
  }
  int asl = ((tid & 3) ^ ((tid >> 3) & 3)) * 16;
  const char* asrc1 = (const char*)(xb + (size_t)srow1 * D) + asl;
  const char* asrc2 = (const char*)(xb + (size_t)srow2 * D) + asl;
  const char* b1t = (const char*)(B1 + (size_t)ntile * (D / 32) * 4096);
  const char* b3t = (const char*)(B3 + (size_t)ntile * (D / 32) * 4096);

  floatx4 accg[4][4], accu[4][4];
#pragma unroll
  for (int i = 0; i < 4; ++i)
#pragma unroll
    for (int j = 0; j < 4; ++j) {
      accg[i][j] = (floatx4){0.f, 0.f, 0.f, 0.f};
      accu[i][j] = (floatx4){0.f, 0.f, 0.f, 0.f};
    }

  auto stage = [&](int kt, unsigned short* Ad, unsigned short* B1d, unsigned short* B3d) {
    size_t ko = (size_t)kt * 64;     // A advances 32 bf16 = 64 B per K-step
    size_t bo = (size_t)kt * 8192;   // B tile = 8 KB per K-step
    glds16(asrc1 + ko, (char*)Ad + lw);
    glds16(asrc2 + ko, (char*)Ad + 4096 + lw);
    glds16(b1t + bo + swzb, (char*)B1d + lw);
    glds16(b1t + bo + 4096 + swzb, (char*)B1d + 4096 + lw);
    glds16(b3t + bo + swzb, (char*)B3d + lw);
    glds16(b3t + bo + 4096 + swzb, (char*)B3d + 4096 + lw);
  };
  auto compute = [&](const unsigned short* Ac, const unsigned short* B1c,
                     const unsigned short* B3c) {
    short8 af[4], b1f[4], b3f[4];
#pragma unroll
    for (int mi = 0; mi < 4; ++mi)
      af[mi] = *(const short8*)(Ac + (wm * 64 + mi * 16 + row16) * 32 + qsw8);
#pragma unroll
    for (int ni = 0; ni < 4; ++ni) {
      b1f[ni] = *(const short8*)(B1c + (wn * 64 + ni * 16 + row16) * 32 + qsw8);
      b3f[ni] = *(const short8*)(B3c + (wn * 64 + ni * 16 + row16) * 32 + qsw8);
    }
#pragma unroll
    for (int mi = 0; mi < 4; ++mi)
#pragma unroll
      for (int ni = 0; ni < 4; ++ni) {
        accg[mi][ni] = __builtin_amdgcn_mfma_f32_16x16x32_bf16(af[mi], b1f[ni], accg[mi][ni], 0, 0, 0);
        accu[mi][ni] = __builtin_amdgcn_mfma_f32_16x16x32_bf16(af[mi], b3f[ni], accu[mi][ni], 0, 0, 0);
      }
  };

  stage(0, Au0, B1u0, B3u0);
  stage(1, Au1, B1u1, B3u1);
  asm volatile("s_waitcnt vmcnt(6)" ::: "memory");   // stage(0) landed
  __builtin_amdgcn_s_barrier();
  for (int t = 0; t < 30; t += 3) {
    stage(t + 2, Au2, B1u2, B3u2);
    compute(Au0, B1u0, B3u0);
    asm volatile("s_waitcnt vmcnt(6)" ::: "memory");
    __builtin_amdgcn_s_barrier();
    stage(t + 3, Au0, B1u0, B3u0);
    compute(Au1, B1u1, B3u1);
    asm volatile("s_waitcnt vmcnt(6)" ::: "memory");
    __builtin_amdgcn_s_barrier();
    stage(t + 4, Au1, B1u1, B3u1);
    compute(Au2, B1u2, B3u2);
    asm volatile("s_waitcnt vmcnt(6)" ::: "memory");
    __builtin_amdgcn_s_barrier();
  }
  compute(Au0, B1u0, B3u0);            // t=30
  asm volatile("s_waitcnt vmcnt(0)" ::: "memory");   // stage(31) landed
  __builtin_amdgcn_s_barrier();
  compute(Au1, B1u1, B3u1);            // t=31

  // epilogue: silu(g)*u -> bf16, H in tiled layout
#pragma unroll
  for (int mi = 0; mi < 4; ++mi)
#pragma unroll
    for (int ni = 0; ni < 4; ++ni)
#pragma unroll
      for (int r = 0; r < 4; ++r) {
        int hrow = mt * 128 + wm * 64 + mi * 16 + quad * 4 + r;
        int col = ntile * 128 + wn * 64 + ni * 16 + row16;
        float g = accg[mi][ni][r], u = accu[mi][ni][r];
        float h = g * u / (1.0f + __expf(-g));
        size_t o = ((size_t)(hrow >> 7) * 128 + (col >> 5)) * 4096 + (size_t)(hrow & 127) * 32 + (col & 31);
        Hb[o] = f2bf(h);
      }
}

// ---------------- down GEMM: O = (H @ W2) * gate_scale, full-K ----------------
// Same depth-2 counted-vmcnt pipeline; stage width = 4 glds -> vmcnt(4). 128 K-steps.
__global__ __launch_bounds__(256, 2) void down_gemm(
    const unsigned short* __restrict__ Hb, const unsigned short* __restrict__ W2T,
    const unsigned short* __restrict__ W2sT, const int* __restrict__ cnt,
    const float* __restrict__ list_gate, float* __restrict__ O) {
  int mt = blockIdx.y, ntile = blockIdx.x;
  int obase, ccnt;
  int e = route(cnt, mt * 128, obase, ccnt);
  if (e < 0) return;
  const char* Bt = (const char*)(((e < E) ? (W2T + (size_t)e * D * F) : W2sT)
                                 + (size_t)ntile * (F / 32) * 4096);
  const char* At = (const char*)(Hb + (size_t)mt * (F / 32) * 4096);
  __shared__ unsigned short Ad0[128 * 32], Bd0[128 * 32];
  __shared__ unsigned short Ad1[128 * 32], Bd1[128 * 32];
  __shared__ unsigned short Ad2[128 * 32], Bd2[128 * 32];
  int tid = threadIdx.x;
  int lane = tid & 63, wv = tid >> 6, wm = wv >> 1, wn = wv & 1;
  int row16 = lane & 15, quad = lane >> 4;
  int qsw8 = (quad ^ ((lane >> 1) & 3)) * 8;
  int swzb = (tid >> 2) * 64 + (((tid & 3) ^ ((tid >> 3) & 3)) * 16);
  int lw = wv * 1024;
  floatx4 acc[4][4];
#pragma unroll
  for (int i = 0; i < 4; ++i)
#pragma unroll
    for (int j = 0; j < 4; ++j) acc[i][j] = (floatx4){0.f, 0.f, 0.f, 0.f};

  auto stage = [&](int kt, unsigned short* Ad, unsigned short* Bd) {
    size_t o = (size_t)kt * 8192;
    glds16(At + o + swzb, (char*)Ad + lw);
    glds16(At + o + 4096 + swzb, (char*)Ad + 4096 + lw);
    glds16(Bt + o + swzb, (char*)Bd + lw);
    glds16(Bt + o + 4096 + swzb, (char*)Bd + 4096 + lw);
  };
  auto compute = [&](const unsigned short* Ac, const unsigned short* Bc) {
    short8 af[4], bf[4];
#pragma unroll
    for (int mi = 0; mi < 4; ++mi)
      af[mi] = *(const short8*)(Ac + (wm * 64 + mi * 16 + row16) * 32 + qsw8);
#pragma unroll
    for (int ni = 0; ni < 4; ++ni)
      bf[ni] = *(const short8*)(Bc + (wn * 64 + ni * 16 + row16) * 32 + qsw8);
#pragma unroll
    for (int mi = 0; mi < 4; ++mi)
#pragma unroll
      for (int ni = 0; ni < 4; ++ni)
        acc[mi][ni] = __builtin_amdgcn_mfma_f32_16x16x32_bf16(af[mi], bf[ni], acc[mi][ni], 0, 0, 0);
  };

  stage(0, Ad0, Bd0);
  stage(1, Ad1, Bd1);
  asm volatile("s_waitcnt vmcnt(4)" ::: "memory");   // stage(0) landed
  __builtin_amdgcn_s_barrier();
  for (int t = 0; t < 126; t += 3) {
    stage(t + 2, Ad2, Bd2);
    compute(Ad0, Bd0);
    asm volatile("s_waitcnt vmcnt(4)" ::: "memory");
    __builtin_amdgcn_s_barrier();
    stage(t + 3, Ad0, Bd0);
    compute(Ad1, Bd1);
    asm volatile("s_waitcnt vmcnt(4)" ::: "memory");
    __builtin_amdgcn_s_barrier();
    stage(t + 4, Ad1, Bd1);
    compute(Ad2, Bd2);
    asm volatile("s_waitcnt vmcnt(4)" ::: "memory");
    __builtin_amdgcn_s_barrier();
  }
  compute(Ad0, Bd0);                   // t=126
  asm volatile("s_waitcnt vmcnt(0)" ::: "memory");   // stage(127) landed
  __builtin_amdgcn_s_barrier();
  compute(Ad1, Bd1);                   // t=127

#pragma unroll
  for (int mi = 0; mi < 4; ++mi)
#pragma unroll
    for (int ni = 0; ni < 4; ++ni)
#pragma unroll
      for (int r = 0; r < 4; ++r) {
        int grow = mt * 128 + wm * 64 + mi * 16 + quad * 4 + r;
        int col = ntile * 128 + wn * 64 + ni * 16 + row16;
        float scale;
        if (e < E) {
          int i = grow - obase;
          scale = (i < ccnt) ? 0.5f * list_gate[e * T + i] : 0.0f;
        } else {
          scale = 0.0625f;
        }
        O[(size_t)grow * D + col] = acc[mi][ni][r] * scale;
      }
}

// ---------------- combine: out = r0 + r1 + shared (rows from assign+cnt) ----------------
__global__ void combine_kernel(const float* __restrict__ O, const int* __restrict__ cnt,
                               const int* __restrict__ assign, float* __restrict__ out) {
  int idx = blockIdx.x * 256 + threadIdx.x;  // T * D/4
  int t = idx >> 8, c = idx & 255;
  int a0 = assign[2 * t], a1 = assign[2 * t + 1];
  int r0 = seg_off(cnt, a0 >> 16) + (a0 & 0xFFFF);
  int r1 = seg_off(cnt, a1 >> 16) + (a1 & 0xFFFF);
  const float4* O4 = (const float4*)O;
  float4 a = O4[(size_t)r0 * 256 + c];
  float4 b = O4[(size_t)r1 * 256 + c];
  float4 s = O4[((size_t)SHB + t) * 256 + c];
  float4 r;
  r.x = a.x + b.x + s.x;
  r.y = a.y + b.y + s.y;
  r.z = a.z + b.z + s.z;
  r.w = a.w + b.w + s.w;
  ((float4*)out)[idx] = r;
}

extern "C" void kernel_launch(void* const* d_in, const int* in_sizes, int n_in,
                              void* d_out, int out_size, void* d_ws, size_t ws_size,
                              hipStream_t stream) {
  (void)in_sizes; (void)n_in; (void)out_size; (void)ws_size;
  const float* x   = (const float*)d_in[0];
  const float* gW  = (const float*)d_in[1];
  const float* w1e = (const float*)d_in[2];
  const float* w3e = (const float*)d_in[3];
  const float* w2e = (const float*)d_in[4];
  const float* w1s = (const float*)d_in[5];
  const float* w3s = (const float*)d_in[6];
  const float* w2s = (const float*)d_in[7];
  float* out = (float*)d_out;

  char* w = (char*)d_ws;
  auto alloc = [&](size_t bytes) {
    char* p = w; w += (bytes + 255) & ~(size_t)255; return p;
  };
  unsigned short* xb   = (unsigned short*)alloc((size_t)T * D * 2);
  unsigned short* W1T  = (unsigned short*)alloc((size_t)E * F * D * 2);
  unsigned short* W3T  = (unsigned short*)alloc((size_t)E * F * D * 2);
  unsigned short* W2T  = (unsigned short*)alloc((size_t)E * D * F * 2);
  unsigned short* W1sT = (unsigned short*)alloc((size_t)F * D * 2);
  unsigned short* W3sT = (unsigned short*)alloc((size_t)F * D * 2);
  unsigned short* W2sT = (unsigned short*)alloc((size_t)D * F * 2);
  unsigned short* Hb   = (unsigned short*)alloc((size_t)NROWS * F * 2);
  float* Ob        = (float*)alloc((size_t)NROWS * D * 4);
  float* list_gate = (float*)alloc((size_t)E * T * 4);
  int* list_tok    = (int*)alloc((size_t)E * T * 4);
  int* assign      = (int*)alloc((size_t)T * 2 * 4);
  int* cnt         = (int*)alloc(E * 4);

  hipMemsetAsync(cnt, 0, E * 4, stream);
  prep_kernel<<<29696, 256, 0, stream>>>(x, gW, w1e, w3e, w2e, w1s, w3s, w2s,
                                         W1T, W3T, W2T, W1sT, W3sT, W2sT,
                                         xb, cnt, list_tok, list_gate, assign);
  up_gemm<<<dim3(F / 128, MT_MAX), 256, 0, stream>>>(xb, W1T, W3T, W1sT, W3sT,
                                                     cnt, list_tok, Hb);
  down_gemm<<<dim3(D / 128, MT_MAX), 256, 0, stream>>>(Hb, W2T, W2sT, cnt, list_gate, Ob);
  combine_kernel<<<(T * D / 4) / 256, 256, 0, stream>>>(Ob, cnt, assign, out);
}